// Round 1
// baseline (491.973 us; speedup 1.0000x reference)
//
#include <hip/hip_runtime.h>
#include <stdint.h>

namespace {

constexpr int Bb = 8, S = 4096, D = 1024, BS = 32768;
constexpr float SCALE = 0.08838834764831845f;           // (D/NUM_HEADS)^-0.5
constexpr float FEPS  = 1.1920928955078125e-07f;        // float32 eps (2^-23)

typedef unsigned short u16;
typedef __attribute__((ext_vector_type(8))) __bf16 bf16x8;
typedef __attribute__((ext_vector_type(4))) float   f32x4;

__device__ __forceinline__ u16 f2bf(float f) {          // RNE f32 -> bf16 (finite inputs)
  uint32_t x = __float_as_uint(f);
  x += 0x7fffu + ((x >> 16) & 1u);
  return (u16)(x >> 16);
}
__device__ __forceinline__ float bf2f(u16 u) {
  return __uint_as_float(((uint32_t)u) << 16);
}
__device__ __forceinline__ void gload_lds16(const u16* g, u16* l) {
  __builtin_amdgcn_global_load_lds((__attribute__((address_space(1))) void*)g,
                                   (__attribute__((address_space(3))) void*)l, 16, 0, 0);
}

// ---------------------------------------------------------------- prep_h
// h = (hidden + pos) / max(||.||2, 1e-12), split into bf16 hi/lo pair.
__global__ void prep_h(const float* __restrict__ hidden, const float* __restrict__ pos,
                       u16* __restrict__ Hhi, u16* __restrict__ Hlo) {
  const int r = blockIdx.x;          // row in [0, BS)
  const int t = threadIdx.x;         // 256 threads, 4 elems each
  const float4 hv = ((const float4*)(hidden + (size_t)r * D))[t];
  const float4 pv = ((const float4*)(pos + (size_t)(r & (S - 1)) * D))[t];
  float x0 = hv.x + pv.x, x1 = hv.y + pv.y, x2 = hv.z + pv.z, x3 = hv.w + pv.w;
  float ss = x0 * x0 + x1 * x1 + x2 * x2 + x3 * x3;
  #pragma unroll
  for (int m = 1; m < 64; m <<= 1) ss += __shfl_xor(ss, m, 64);
  __shared__ float red[4];
  if ((t & 63) == 0) red[t >> 6] = ss;
  __syncthreads();
  const float nrm = fmaxf(sqrtf(red[0] + red[1] + red[2] + red[3]), 1e-12f);
  const float h0 = x0 / nrm, h1 = x1 / nrm, h2 = x2 / nrm, h3 = x3 / nrm;
  const u16 a0 = f2bf(h0), a1 = f2bf(h1), a2 = f2bf(h2), a3 = f2bf(h3);
  ((ushort4*)(Hhi + (size_t)r * D))[t] = make_ushort4(a0, a1, a2, a3);
  ((ushort4*)(Hlo + (size_t)r * D))[t] = make_ushort4(
      f2bf(h0 - bf2f(a0)), f2bf(h1 - bf2f(a1)), f2bf(h2 - bf2f(a2)), f2bf(h3 - bf2f(a3)));
}

// ---------------------------------------------------------------- gemm_G
// G[i][j] = sum_k Wq[k][i] * Wk[k][j]  (f32), written as bf16 hi/lo split.
__global__ void gemm_G(const float* __restrict__ Wq, const float* __restrict__ Wk,
                       u16* __restrict__ Ghi, u16* __restrict__ Glo) {
  __shared__ float Qs[32][64];
  __shared__ float Ks[32][64];
  const int t = threadIdx.x;
  const int i0 = blockIdx.x * 64, j0 = blockIdx.y * 64;
  const int tx = t & 15, ty = t >> 4;
  float acc[4][4] = {};
  for (int k0 = 0; k0 < D; k0 += 32) {
    #pragma unroll
    for (int q = 0; q < 2; ++q) {
      const int c = t + q * 256;
      const int row = c >> 4, c4 = (c & 15) << 2;
      *(float4*)&Qs[row][c4] = *(const float4*)&Wq[(size_t)(k0 + row) * D + i0 + c4];
      *(float4*)&Ks[row][c4] = *(const float4*)&Wk[(size_t)(k0 + row) * D + j0 + c4];
    }
    __syncthreads();
    #pragma unroll 8
    for (int kk = 0; kk < 32; ++kk) {
      const float4 qa = *(const float4*)&Qs[kk][tx << 2];
      const float4 kb = *(const float4*)&Ks[kk][ty << 2];
      const float qq[4] = {qa.x, qa.y, qa.z, qa.w};
      const float kv[4] = {kb.x, kb.y, kb.z, kb.w};
      #pragma unroll
      for (int a = 0; a < 4; ++a)
        #pragma unroll
        for (int bj = 0; bj < 4; ++bj) acc[a][bj] = fmaf(qq[a], kv[bj], acc[a][bj]);
    }
    __syncthreads();
  }
  #pragma unroll
  for (int a = 0; a < 4; ++a) {
    const int i = i0 + (tx << 2) + a;
    u16 hb[4], lb[4];
    #pragma unroll
    for (int bj = 0; bj < 4; ++bj) {
      const float g = acc[a][bj];
      hb[bj] = f2bf(g);
      lb[bj] = f2bf(g - bf2f(hb[bj]));
    }
    const size_t base = (size_t)i * D + j0 + (ty << 2);
    *(ushort4*)&Ghi[base] = make_ushort4(hb[0], hb[1], hb[2], hb[3]);
    *(ushort4*)&Glo[base] = make_ushort4(lb[0], lb[1], lb[2], lb[3]);
  }
}

// ---------------------------------------------------------------- gemm_main
// bf16x3 split GEMM:  U[r,i] = sum_j Hf32[r,j] * Gf32[i,j]  via
// (Hhi,Ghi)+(Hlo,Ghi)+(Hhi,Glo), K extended to 3*1024.  Fused epilogue:
// adj_part[nt][r] = sum_{i in tile} U[r,i] * Hf32[r+1,i]  (deterministic partials).
__global__ __launch_bounds__(256) void gemm_main(
    const u16* __restrict__ Hhi, const u16* __restrict__ Hlo,
    const u16* __restrict__ Ghi, const u16* __restrict__ Glo,
    float* __restrict__ adj_part) {
  __shared__ u16 As[2][128 * 32];
  __shared__ u16 Bs[2][128 * 32];
  __shared__ float adjp[2][128];
  const int tid = threadIdx.x;
  const int mt = blockIdx.x >> 3, nt = blockIdx.x & 7;
  const int r0 = mt << 7, n0 = nt << 7;
  const int lane = tid & 63, wave = tid >> 6;
  const int wr = (wave >> 1) << 6;       // wave row offset (0/64)
  const int wc = (wave & 1) << 6;        // wave col offset (0/64)
  const int frow = lane & 15;
  const int fk = (lane >> 4) << 3;

  f32x4 acc[4][4];
  #pragma unroll
  for (int m = 0; m < 4; ++m)
    #pragma unroll
    for (int n = 0; n < 4; ++n) acc[m][n] = (f32x4){0.f, 0.f, 0.f, 0.f};

  auto stage = [&](int sel, int kt) {
    const u16* Ab = (kt < 32) ? Hhi : (kt < 64 ? Hlo : Hhi);
    const u16* Bt = (kt < 64) ? Ghi : Glo;
    const int k0 = (kt & 31) << 5;
    #pragma unroll
    for (int q = 0; q < 2; ++q) {
      const int c = tid + (q << 8);
      const int row = c >> 2, cc = (c & 3) << 3;
      gload_lds16(Ab + (size_t)(r0 + row) * D + k0 + cc, &As[sel][(size_t)c << 3]);
      gload_lds16(Bt + (size_t)(n0 + row) * D + k0 + cc, &Bs[sel][(size_t)c << 3]);
    }
  };
  auto compute = [&](int sel) {
    bf16x8 af[4], bfr[4];
    #pragma unroll
    for (int m = 0; m < 4; ++m)
      af[m] = *(const bf16x8*)&As[sel][((wr + (m << 4) + frow) << 5) + fk];
    #pragma unroll
    for (int n = 0; n < 4; ++n)
      bfr[n] = *(const bf16x8*)&Bs[sel][((wc + (n << 4) + frow) << 5) + fk];
    #pragma unroll
    for (int m = 0; m < 4; ++m)
      #pragma unroll
      for (int n = 0; n < 4; ++n)
        acc[m][n] = __builtin_amdgcn_mfma_f32_16x16x32_bf16(af[m], bfr[n], acc[m][n], 0, 0, 0);
  };

  stage(0, 0);
  __syncthreads();
  int sel = 0;
  for (int kt = 0; kt < 96; ++kt) {
    if (kt < 95) stage(sel ^ 1, kt + 1);
    compute(sel);
    __syncthreads();
    sel ^= 1;
  }

  // epilogue: rowwise dot with shifted h (f32 = hi + lo), reduce over 16 lanes
  #pragma unroll
  for (int m = 0; m < 4; ++m) {
    #pragma unroll
    for (int reg = 0; reg < 4; ++reg) {
      const int rl = wr + (m << 4) + ((lane >> 4) << 2) + reg;
      const int gr = r0 + rl;
      const bool valid = ((gr + 1) & (S - 1)) != 0;   // pair (gr, gr+1) within batch
      float sum = 0.f;
      if (valid) {
        const size_t nb = (size_t)(gr + 1) * D;
        #pragma unroll
        for (int n = 0; n < 4; ++n) {
          const int gc = n0 + wc + (n << 4) + frow;
          const float hn = bf2f(Hhi[nb + gc]) + bf2f(Hlo[nb + gc]);
          sum = fmaf(acc[m][n][reg], hn, sum);
        }
      }
      #pragma unroll
      for (int off = 1; off < 16; off <<= 1) sum += __shfl_xor(sum, off, 64);
      if (frow == 0) adjp[wave & 1][rl] = sum;
    }
  }
  __syncthreads();
  if (tid < 128) adj_part[(size_t)nt * BS + r0 + tid] = adjp[0][tid] + adjp[1][tid];
}

// ---------------------------------------------------------------- decide_scan
// scores -> RelaxedBernoulli -> hard bits -> per-batch cumsum -> segment starts.
__global__ void decide_scan(const float* __restrict__ adj_part,
                            const float* __restrict__ sig_temp, const float* __restrict__ sig_thr,
                            const float* __restrict__ noise_u,
                            int* __restrict__ seg_start, int* __restrict__ nseg_out,
                            float* __restrict__ kf_out) {
  const int b = blockIdx.x, t = threadIdx.x;
  __shared__ int ssum[256];
  const float temp = sig_temp[0], thr = sig_thr[0];
  int hard[16];
  int loc = 0;
  #pragma unroll
  for (int e = 0; e < 16; ++e) {
    const int s = (t << 4) + e;
    float score = 0.f;
    if (s > 0) {
      const int r = b * S + s - 1;
      float a = 0.f;
      #pragma unroll
      for (int p = 0; p < 8; ++p) a += adj_part[(size_t)p * BS + r];
      score = a * SCALE;
    }
    float pr = 1.f / (1.f + expf(-(score - thr) / temp));
    pr = fminf(fmaxf(pr, 0.f), 1.f);
    if (s == 0) pr = 1.f;
    const float p = fminf(fmaxf(pr, FEPS), 1.f - FEPS);
    const float lgt = logf(p) - log1pf(-p);
    const float uu = fminf(fmaxf(noise_u[b * S + s], FEPS), 1.f - FEPS);
    const float lgs = logf(uu) - log1pf(-uu);
    const float soft = 1.f / (1.f + expf(-(lgt + lgs)));
    hard[e] = (soft > 0.5f) ? 1 : 0;
    loc += hard[e];
  }
  ssum[t] = loc;
  __syncthreads();
  for (int off = 1; off < 256; off <<= 1) {
    int v = ssum[t];
    if (t >= off) v += ssum[t - off];
    __syncthreads();
    ssum[t] = v;
    __syncthreads();
  }
  const int ktot = ssum[255];
  int cum = ssum[t] - loc;                 // exclusive prefix
  #pragma unroll
  for (int e = 0; e < 16; ++e) {
    const int s = (t << 4) + e;
    const int pseg = min(max(cum - 1, 0), S - 1);
    cum += hard[e];
    const int seg = min(max(cum - 1, 0), S - 1);
    if (s == 0 || seg != pseg) seg_start[b * S + seg] = s;
  }
  if (t == 0) {
    nseg_out[b] = min(max(ktot, 1), S);
    kf_out[b] = (float)ktot;
  }
}

// ---------------------------------------------------------------- pool
// out[j, b, :] = mean over segment j of h rows (hi+lo), zeros for j >= nseg.
__global__ void pool(const u16* __restrict__ Hhi, const u16* __restrict__ Hlo,
                     const int* __restrict__ seg_start, const int* __restrict__ nseg_arr,
                     float* __restrict__ out) {
  const int j = blockIdx.x, b = blockIdx.y, t = threadIdx.x;
  const int ns = nseg_arr[b];
  float4* o = (float4*)(out + (((size_t)j * Bb + b) << 10));
  if (j >= ns) {
    o[t] = (float4){0.f, 0.f, 0.f, 0.f};
    return;
  }
  const int s0 = seg_start[b * S + j];
  const int s1 = (j + 1 < ns) ? seg_start[b * S + j + 1] : S;
  float a0 = 0.f, a1 = 0.f, a2 = 0.f, a3 = 0.f;
  for (int s = s0; s < s1; ++s) {
    const size_t base = (((size_t)b * S + s) << 10) + (t << 2);
    const ushort4 hi = *(const ushort4*)(Hhi + base);
    const ushort4 lo = *(const ushort4*)(Hlo + base);
    a0 += bf2f(hi.x) + bf2f(lo.x);
    a1 += bf2f(hi.y) + bf2f(lo.y);
    a2 += bf2f(hi.z) + bf2f(lo.z);
    a3 += bf2f(hi.w) + bf2f(lo.w);
  }
  const float c = (float)(s1 - s0);
  o[t] = (float4){a0 / c, a1 / c, a2 / c, a3 / c};
}

// ---------------------------------------------------------------- loss
__global__ void loss_k(const float* __restrict__ kf, float* __restrict__ out) {
  const int t = threadIdx.x;
  float lp = 0.f;
  if (t < 8) {
    const float n = 4096.f;
    const float k = kf[t];
    lp = lgammaf(n + 1.f) - lgammaf(k + 1.f) - lgammaf(n - k + 1.f)
       + k * logf(0.2f) + (n - k) * log1pf(-0.2f);
  }
  #pragma unroll
  for (int off = 1; off < 8; off <<= 1) lp += __shfl_xor(lp, off, 64);
  if (t == 0) out[(size_t)BS * 1024] = -(lp / 8.f) / 4096.f;
}

}  // namespace

extern "C" void kernel_launch(void* const* d_in, const int* in_sizes, int n_in,
                              void* d_out, int out_size, void* d_ws, size_t ws_size,
                              hipStream_t stream) {
  (void)in_sizes; (void)n_in; (void)out_size; (void)ws_size;
  const float* hidden = (const float*)d_in[0];
  const float* pos    = (const float*)d_in[1];
  const float* Wq     = (const float*)d_in[2];
  const float* Wk     = (const float*)d_in[3];
  const float* stemp  = (const float*)d_in[4];
  const float* sthr   = (const float*)d_in[5];
  const float* nois   = (const float*)d_in[6];
  float* out = (float*)d_out;
  char* ws = (char*)d_ws;

  // workspace layout (bytes)
  u16*   Hhi       = (u16*)(ws);                       // 67,108,864
  u16*   Hlo       = (u16*)(ws + 67108864);            // 67,108,864
  u16*   Ghi       = (u16*)(ws + 134217728);           //  2,097,152
  u16*   Glo       = (u16*)(ws + 136314880);           //  2,097,152
  float* adj_part  = (float*)(ws + 138412032);         //  1,048,576 (8 x BS f32)
  int*   seg_start = (int*)(ws + 139460608);           //    131,072
  int*   nseg      = (int*)(ws + 139591680);           //         32
  float* kf        = (float*)(ws + 139591936);         //         32

  hipLaunchKernelGGL(prep_h,      dim3(BS),       dim3(256), 0, stream, hidden, pos, Hhi, Hlo);
  hipLaunchKernelGGL(gemm_G,      dim3(16, 16),   dim3(256), 0, stream, Wq, Wk, Ghi, Glo);
  hipLaunchKernelGGL(gemm_main,   dim3(2048),     dim3(256), 0, stream, Hhi, Hlo, Ghi, Glo, adj_part);
  hipLaunchKernelGGL(decide_scan, dim3(Bb),       dim3(256), 0, stream, adj_part, stemp, sthr, nois, seg_start, nseg, kf);
  hipLaunchKernelGGL(pool,        dim3(S, Bb),    dim3(256), 0, stream, Hhi, Hlo, seg_start, nseg, out);
  hipLaunchKernelGGL(loss_k,      dim3(1),        dim3(64),  0, stream, kf, out);
}

// Round 2
// 417.986 us; speedup vs baseline: 1.1770x; 1.1770x over previous
//
#include <hip/hip_runtime.h>
#include <stdint.h>

namespace {

constexpr int Bb = 8, S = 4096, D = 1024, BS = 32768;
constexpr float SCALE = 0.08838834764831845f;           // (D/NUM_HEADS)^-0.5
constexpr float FEPS  = 1.1920928955078125e-07f;        // float32 eps (2^-23)

typedef unsigned short u16;
typedef __attribute__((ext_vector_type(8))) _Float16 f16x8;
typedef __attribute__((ext_vector_type(4))) float    f32x4;

__device__ __forceinline__ u16 f2h(float f) {
  _Float16 h = (_Float16)f;
  return __builtin_bit_cast(u16, h);
}
__device__ __forceinline__ float h2f(u16 u) {
  return (float)__builtin_bit_cast(_Float16, u);
}
__device__ __forceinline__ void gload_lds16(const u16* g, u16* l) {
  __builtin_amdgcn_global_load_lds((__attribute__((address_space(1))) void*)g,
                                   (__attribute__((address_space(3))) void*)l, 16, 0, 0);
}

// ---------------------------------------------------------------- prep_h
// h = (hidden + pos) / max(||.||2, 1e-12), stored f16. Also zeroes fcnt.
__global__ void prep_h(const float* __restrict__ hidden, const float* __restrict__ pos,
                       u16* __restrict__ Hf, int* __restrict__ fcnt) {
  if (blockIdx.x == 0 && threadIdx.x == 0) *fcnt = 0;
  const int r = blockIdx.x;          // row in [0, BS)
  const int t = threadIdx.x;         // 256 threads, 4 elems each
  const float4 hv = ((const float4*)(hidden + (size_t)r * D))[t];
  const float4 pv = ((const float4*)(pos + (size_t)(r & (S - 1)) * D))[t];
  float x0 = hv.x + pv.x, x1 = hv.y + pv.y, x2 = hv.z + pv.z, x3 = hv.w + pv.w;
  float ss = x0 * x0 + x1 * x1 + x2 * x2 + x3 * x3;
  #pragma unroll
  for (int m = 1; m < 64; m <<= 1) ss += __shfl_xor(ss, m, 64);
  __shared__ float red[4];
  if ((t & 63) == 0) red[t >> 6] = ss;
  __syncthreads();
  const float nrm = fmaxf(sqrtf(red[0] + red[1] + red[2] + red[3]), 1e-12f);
  ((ushort4*)(Hf + (size_t)r * D))[t] = make_ushort4(
      f2h(x0 / nrm), f2h(x1 / nrm), f2h(x2 / nrm), f2h(x3 / nrm));
}

// ---------------------------------------------------------------- gemm_G
// G[i][j] = sum_k Wq[k][i] * Wk[k][j], stored f32 (exact path) + f16 (MFMA path).
__global__ void gemm_G(const float* __restrict__ Wq, const float* __restrict__ Wk,
                       float* __restrict__ Gf32, u16* __restrict__ Gf16) {
  __shared__ float Qs[32][64];
  __shared__ float Ks[32][64];
  const int t = threadIdx.x;
  const int i0 = blockIdx.x * 64, j0 = blockIdx.y * 64;
  const int tx = t & 15, ty = t >> 4;
  float acc[4][4] = {};
  for (int k0 = 0; k0 < D; k0 += 32) {
    #pragma unroll
    for (int q = 0; q < 2; ++q) {
      const int c = t + q * 256;
      const int row = c >> 4, c4 = (c & 15) << 2;
      *(float4*)&Qs[row][c4] = *(const float4*)&Wq[(size_t)(k0 + row) * D + i0 + c4];
      *(float4*)&Ks[row][c4] = *(const float4*)&Wk[(size_t)(k0 + row) * D + j0 + c4];
    }
    __syncthreads();
    #pragma unroll 8
    for (int kk = 0; kk < 32; ++kk) {
      const float4 qa = *(const float4*)&Qs[kk][tx << 2];
      const float4 kb = *(const float4*)&Ks[kk][ty << 2];
      const float qq[4] = {qa.x, qa.y, qa.z, qa.w};
      const float kv[4] = {kb.x, kb.y, kb.z, kb.w};
      #pragma unroll
      for (int a = 0; a < 4; ++a)
        #pragma unroll
        for (int bj = 0; bj < 4; ++bj) acc[a][bj] = fmaf(qq[a], kv[bj], acc[a][bj]);
    }
    __syncthreads();
  }
  #pragma unroll
  for (int a = 0; a < 4; ++a) {
    const int i = i0 + (tx << 2) + a;
    const size_t base = (size_t)i * D + j0 + (ty << 2);
    *(float4*)&Gf32[base] = make_float4(acc[a][0], acc[a][1], acc[a][2], acc[a][3]);
    *(ushort4*)&Gf16[base] = make_ushort4(
        f2h(acc[a][0]), f2h(acc[a][1]), f2h(acc[a][2]), f2h(acc[a][3]));
  }
}

// ---------------------------------------------------------------- gemm_main
// fp16 MFMA GEMM: U[r,i] = sum_j Hf[r,j] * Gf[i,j]  (f32 accum).  Fused epilogue:
// adj_part[nt][r] = sum_{i in tile} U[r,i] * Hf[r+1,i]  (deterministic partials).
__global__ __launch_bounds__(256) void gemm_main(
    const u16* __restrict__ Hf, const u16* __restrict__ Gf,
    float* __restrict__ adj_part) {
  __shared__ u16 As[2][128 * 32];
  __shared__ u16 Bs[2][128 * 32];
  __shared__ float adjp[2][128];
  const int tid = threadIdx.x;
  const int mt = blockIdx.x >> 3, nt = blockIdx.x & 7;
  const int r0 = mt << 7, n0 = nt << 7;
  const int lane = tid & 63, wave = tid >> 6;
  const int wr = (wave >> 1) << 6;       // wave row offset (0/64)
  const int wc = (wave & 1) << 6;        // wave col offset (0/64)
  const int frow = lane & 15;
  const int fk = (lane >> 4) << 3;

  f32x4 acc[4][4];
  #pragma unroll
  for (int m = 0; m < 4; ++m)
    #pragma unroll
    for (int n = 0; n < 4; ++n) acc[m][n] = (f32x4){0.f, 0.f, 0.f, 0.f};

  auto stage = [&](int sel, int kt) {
    const int k0 = kt << 5;
    #pragma unroll
    for (int q = 0; q < 2; ++q) {
      const int c = tid + (q << 8);
      const int row = c >> 2, cc = (c & 3) << 3;
      gload_lds16(Hf + (size_t)(r0 + row) * D + k0 + cc, &As[sel][(size_t)c << 3]);
      gload_lds16(Gf + (size_t)(n0 + row) * D + k0 + cc, &Bs[sel][(size_t)c << 3]);
    }
  };
  auto compute = [&](int sel) {
    f16x8 af[4], bfr[4];
    #pragma unroll
    for (int m = 0; m < 4; ++m)
      af[m] = *(const f16x8*)&As[sel][((wr + (m << 4) + frow) << 5) + fk];
    #pragma unroll
    for (int n = 0; n < 4; ++n)
      bfr[n] = *(const f16x8*)&Bs[sel][((wc + (n << 4) + frow) << 5) + fk];
    #pragma unroll
    for (int m = 0; m < 4; ++m)
      #pragma unroll
      for (int n = 0; n < 4; ++n)
        acc[m][n] = __builtin_amdgcn_mfma_f32_16x16x32_f16(af[m], bfr[n], acc[m][n], 0, 0, 0);
  };

  stage(0, 0);
  __syncthreads();
  int sel = 0;
  for (int kt = 0; kt < 32; ++kt) {
    if (kt < 31) stage(sel ^ 1, kt + 1);
    compute(sel);
    __syncthreads();
    sel ^= 1;
  }

  // epilogue: rowwise dot with shifted h (f16->f32), reduce over 16 lanes
  #pragma unroll
  for (int m = 0; m < 4; ++m) {
    #pragma unroll
    for (int reg = 0; reg < 4; ++reg) {
      const int rl = wr + (m << 4) + ((lane >> 4) << 2) + reg;
      const int gr = r0 + rl;
      const bool valid = ((gr + 1) & (S - 1)) != 0;   // pair (gr, gr+1) within batch
      float sum = 0.f;
      if (valid) {
        const size_t nb = (size_t)(gr + 1) * D;
        #pragma unroll
        for (int n = 0; n < 4; ++n) {
          const int gc = n0 + wc + (n << 4) + frow;
          sum = fmaf(acc[m][n][reg], h2f(Hf[nb + gc]), sum);
        }
      }
      #pragma unroll
      for (int off = 1; off < 16; off <<= 1) sum += __shfl_xor(sum, off, 64);
      if (frow == 0) adjp[wave & 1][rl] = sum;
    }
  }
  __syncthreads();
  if (tid < 128) adj_part[(size_t)nt * BS + r0 + tid] = adjp[0][tid] + adjp[1][tid];
}

// ---------------------------------------------------------------- score_flag
// score[b,s] = SCALE * sum_p adj_part[p][b*S+s-1]; flag near-threshold positions.
__global__ void score_flag(const float* __restrict__ adj_part,
                           const float* __restrict__ sig_temp, const float* __restrict__ sig_thr,
                           const float* __restrict__ noise_u,
                           float* __restrict__ score, int* __restrict__ flags,
                           int* __restrict__ fcnt) {
  const int idx = blockIdx.x * 256 + threadIdx.x;   // position b*S + s
  const int s = idx & (S - 1);
  float sc = 0.f;
  if (s > 0) {
    float a = 0.f;
    #pragma unroll
    for (int p = 0; p < 8; ++p) a += adj_part[(size_t)p * BS + idx - 1];
    sc = a * SCALE;
  }
  score[idx] = sc;
  if (s > 0) {
    const float temp = sig_temp[0], thr = sig_thr[0];
    float pr = 1.f / (1.f + expf(-(sc - thr) / temp));
    pr = fminf(fmaxf(pr, 0.f), 1.f);
    const float p = fminf(fmaxf(pr, FEPS), 1.f - FEPS);
    const float lgt = logf(p) - log1pf(-p);
    const float uu = fminf(fmaxf(noise_u[idx], FEPS), 1.f - FEPS);
    const float lgs = logf(uu) - log1pf(-uu);
    if (fabsf(lgt + lgs) < 1e-3f) {     // margin >> fp16-GEMM score error (~1.3e-6)
      const int k = atomicAdd(fcnt, 1);
      if (k < BS) flags[k] = idx;
    }
  }
}

// ---------------------------------------------------------------- fixup
// Exact f32 recompute of flagged scores: adj = h[idx]' * G * h[idx-1].
__global__ __launch_bounds__(256) void fixup(const int* __restrict__ flags,
    const int* __restrict__ fcnt, const float* __restrict__ hidden,
    const float* __restrict__ pos, const float* __restrict__ Gf32,
    float* __restrict__ score) {
  __shared__ float h0[1024];
  __shared__ float h1[1024];
  __shared__ float red[4];
  const int t = threadIdx.x;
  const int nf = min(*fcnt, BS);
  for (int w = blockIdx.x; w < nf; w += gridDim.x) {
    const int idx = flags[w];
    #pragma unroll
    for (int rr = 0; rr < 2; ++rr) {
      const int r = idx - 1 + rr;
      float* hs = rr ? h1 : h0;
      const float4 hv = ((const float4*)(hidden + (size_t)r * D))[t];
      const float4 pv = ((const float4*)(pos + (size_t)(r & (S - 1)) * D))[t];
      const float x0 = hv.x + pv.x, x1 = hv.y + pv.y, x2 = hv.z + pv.z, x3 = hv.w + pv.w;
      float ss = x0 * x0 + x1 * x1 + x2 * x2 + x3 * x3;
      #pragma unroll
      for (int m = 1; m < 64; m <<= 1) ss += __shfl_xor(ss, m, 64);
      __syncthreads();                       // protect red from previous use
      if ((t & 63) == 0) red[t >> 6] = ss;
      __syncthreads();
      const float nrm = fmaxf(sqrtf(red[0] + red[1] + red[2] + red[3]), 1e-12f);
      hs[4 * t + 0] = x0 / nrm; hs[4 * t + 1] = x1 / nrm;
      hs[4 * t + 2] = x2 / nrm; hs[4 * t + 3] = x3 / nrm;
    }
    __syncthreads();
    float acc = 0.f;
    #pragma unroll
    for (int ii = 0; ii < 4; ++ii) {
      const int i = t + (ii << 8);
      float ti = 0.f;
      for (int j = 0; j < 1024; ++j) ti = fmaf(Gf32[(size_t)i * D + j], h0[j], ti);
      acc = fmaf(h1[i], ti, acc);
    }
    #pragma unroll
    for (int m = 1; m < 64; m <<= 1) acc += __shfl_xor(acc, m, 64);
    __syncthreads();
    if ((t & 63) == 0) red[t >> 6] = acc;
    __syncthreads();
    if (t == 0) score[idx] = (red[0] + red[1] + red[2] + red[3]) * SCALE;
    __syncthreads();
  }
}

// ---------------------------------------------------------------- decide_scan
// scores -> RelaxedBernoulli -> hard bits -> per-batch cumsum -> segment starts.
__global__ void decide_scan(const float* __restrict__ score,
                            const float* __restrict__ sig_temp, const float* __restrict__ sig_thr,
                            const float* __restrict__ noise_u,
                            int* __restrict__ seg_start, int* __restrict__ nseg_out,
                            float* __restrict__ kf_out) {
  const int b = blockIdx.x, t = threadIdx.x;
  __shared__ int ssum[256];
  const float temp = sig_temp[0], thr = sig_thr[0];
  int hard[16];
  int loc = 0;
  #pragma unroll
  for (int e = 0; e < 16; ++e) {
    const int s = (t << 4) + e;
    const float sc = (s > 0) ? score[b * S + s] : 0.f;
    float pr = 1.f / (1.f + expf(-(sc - thr) / temp));
    pr = fminf(fmaxf(pr, 0.f), 1.f);
    if (s == 0) pr = 1.f;
    const float p = fminf(fmaxf(pr, FEPS), 1.f - FEPS);
    const float lgt = logf(p) - log1pf(-p);
    const float uu = fminf(fmaxf(noise_u[b * S + s], FEPS), 1.f - FEPS);
    const float lgs = logf(uu) - log1pf(-uu);
    const float soft = 1.f / (1.f + expf(-(lgt + lgs)));
    hard[e] = (soft > 0.5f) ? 1 : 0;
    loc += hard[e];
  }
  ssum[t] = loc;
  __syncthreads();
  for (int off = 1; off < 256; off <<= 1) {
    int v = ssum[t];
    if (t >= off) v += ssum[t - off];
    __syncthreads();
    ssum[t] = v;
    __syncthreads();
  }
  const int ktot = ssum[255];
  int cum = ssum[t] - loc;                 // exclusive prefix
  #pragma unroll
  for (int e = 0; e < 16; ++e) {
    const int s = (t << 4) + e;
    const int pseg = min(max(cum - 1, 0), S - 1);
    cum += hard[e];
    const int seg = min(max(cum - 1, 0), S - 1);
    if (s == 0 || seg != pseg) seg_start[b * S + seg] = s;
  }
  if (t == 0) {
    nseg_out[b] = min(max(ktot, 1), S);
    kf_out[b] = (float)ktot;
  }
}

// ---------------------------------------------------------------- pool
// out[j, b, :] = mean over segment j of h rows (f16->f32), zeros for j >= nseg.
__global__ void pool(const u16* __restrict__ Hf,
                     const int* __restrict__ seg_start, const int* __restrict__ nseg_arr,
                     float* __restrict__ out) {
  const int j = blockIdx.x, b = blockIdx.y, t = threadIdx.x;
  const int ns = nseg_arr[b];
  float4* o = (float4*)(out + (((size_t)j * Bb + b) << 10));
  if (j >= ns) {
    o[t] = (float4){0.f, 0.f, 0.f, 0.f};
    return;
  }
  const int s0 = seg_start[b * S + j];
  const int s1 = (j + 1 < ns) ? seg_start[b * S + j + 1] : S;
  float a0 = 0.f, a1 = 0.f, a2 = 0.f, a3 = 0.f;
  for (int s = s0; s < s1; ++s) {
    const ushort4 hv = *(const ushort4*)(Hf + (((size_t)b * S + s) << 10) + (t << 2));
    a0 += h2f(hv.x); a1 += h2f(hv.y); a2 += h2f(hv.z); a3 += h2f(hv.w);
  }
  const float c = (float)(s1 - s0);
  o[t] = (float4){a0 / c, a1 / c, a2 / c, a3 / c};
}

// ---------------------------------------------------------------- loss
__global__ void loss_k(const float* __restrict__ kf, float* __restrict__ out) {
  const int t = threadIdx.x;
  float lp = 0.f;
  if (t < 8) {
    const float n = 4096.f;
    const float k = kf[t];
    lp = lgammaf(n + 1.f) - lgammaf(k + 1.f) - lgammaf(n - k + 1.f)
       + k * logf(0.2f) + (n - k) * log1pf(-0.2f);
  }
  #pragma unroll
  for (int off = 1; off < 8; off <<= 1) lp += __shfl_xor(lp, off, 64);
  if (t == 0) out[(size_t)BS * 1024] = -(lp / 8.f) / 4096.f;
}

}  // namespace

extern "C" void kernel_launch(void* const* d_in, const int* in_sizes, int n_in,
                              void* d_out, int out_size, void* d_ws, size_t ws_size,
                              hipStream_t stream) {
  (void)in_sizes; (void)n_in; (void)out_size; (void)ws_size;
  const float* hidden = (const float*)d_in[0];
  const float* pos    = (const float*)d_in[1];
  const float* Wq     = (const float*)d_in[2];
  const float* Wk     = (const float*)d_in[3];
  const float* stemp  = (const float*)d_in[4];
  const float* sthr   = (const float*)d_in[5];
  const float* nois   = (const float*)d_in[6];
  float* out = (float*)d_out;
  char* ws = (char*)d_ws;

  // workspace layout (bytes)
  u16*   Hf        = (u16*)(ws);                       // 67,108,864 (f16 bits)
  u16*   Gf16      = (u16*)(ws + 67108864);            //  2,097,152
  float* Gf32      = (float*)(ws + 69206016);          //  4,194,304
  float* adj_part  = (float*)(ws + 73400320);          //  1,048,576 (8 x BS f32)
  float* score     = (float*)(ws + 74448896);          //    131,072
  int*   flags     = (int*)(ws + 74579968);            //    131,072
  int*   fcnt      = (int*)(ws + 74711040);            //         64
  int*   seg_start = (int*)(ws + 74711104);            //    131,072
  int*   nseg      = (int*)(ws + 74842176);            //         64
  float* kf        = (float*)(ws + 74842240);          //         32

  hipLaunchKernelGGL(prep_h,      dim3(BS),      dim3(256), 0, stream, hidden, pos, Hf, fcnt);
  hipLaunchKernelGGL(gemm_G,      dim3(16, 16),  dim3(256), 0, stream, Wq, Wk, Gf32, Gf16);
  hipLaunchKernelGGL(gemm_main,   dim3(2048),    dim3(256), 0, stream, Hf, Gf16, adj_part);
  hipLaunchKernelGGL(score_flag,  dim3(BS/256),  dim3(256), 0, stream, adj_part, stemp, sthr, nois, score, flags, fcnt);
  hipLaunchKernelGGL(fixup,       dim3(64),      dim3(256), 0, stream, flags, fcnt, hidden, pos, Gf32, score);
  hipLaunchKernelGGL(decide_scan, dim3(Bb),      dim3(256), 0, stream, score, stemp, sthr, nois, seg_start, nseg, kf);
  hipLaunchKernelGGL(pool,        dim3(S, Bb),   dim3(256), 0, stream, Hf, seg_start, nseg, out);
  hipLaunchKernelGGL(loss_k,      dim3(1),       dim3(64),  0, stream, kf, out);
}

// Round 3
// 381.594 us; speedup vs baseline: 1.2893x; 1.0954x over previous
//
#include <hip/hip_runtime.h>
#include <stdint.h>

namespace {

constexpr int Bb = 8, S = 4096, D = 1024, BS = 32768;
constexpr float SCALE = 0.08838834764831845f;           // (D/NUM_HEADS)^-0.5
constexpr float FEPS  = 1.1920928955078125e-07f;        // float32 eps (2^-23)

typedef unsigned short u16;
typedef __attribute__((ext_vector_type(8))) _Float16 f16x8;
typedef __attribute__((ext_vector_type(4))) float    f32x4;

__device__ __forceinline__ u16 f2h(float f) {
  _Float16 h = (_Float16)f;
  return __builtin_bit_cast(u16, h);
}
__device__ __forceinline__ float h2f(u16 u) {
  return (float)__builtin_bit_cast(_Float16, u);
}
__device__ __forceinline__ void gload_lds16(const void* g, void* l) {
  __builtin_amdgcn_global_load_lds((const __attribute__((address_space(1))) void*)g,
                                   (__attribute__((address_space(3))) void*)l, 16, 0, 0);
}
#define VMCNT(n) asm volatile("s_waitcnt vmcnt(" #n ")" ::: "memory")

// ---------------------------------------------------------------- prep_h
// h = (hidden + pos) / max(||.||2, 1e-12), stored f16. Also zeroes fcnt.
__global__ void prep_h(const float* __restrict__ hidden, const float* __restrict__ pos,
                       u16* __restrict__ Hf, int* __restrict__ fcnt) {
  if (blockIdx.x == 0 && threadIdx.x == 0) *fcnt = 0;
  const int r = blockIdx.x;          // row in [0, BS)
  const int t = threadIdx.x;         // 256 threads, 4 elems each
  const float4 hv = ((const float4*)(hidden + (size_t)r * D))[t];
  const float4 pv = ((const float4*)(pos + (size_t)(r & (S - 1)) * D))[t];
  float x0 = hv.x + pv.x, x1 = hv.y + pv.y, x2 = hv.z + pv.z, x3 = hv.w + pv.w;
  float ss = x0 * x0 + x1 * x1 + x2 * x2 + x3 * x3;
  #pragma unroll
  for (int m = 1; m < 64; m <<= 1) ss += __shfl_xor(ss, m, 64);
  __shared__ float red[4];
  if ((t & 63) == 0) red[t >> 6] = ss;
  __syncthreads();
  const float nrm = fmaxf(sqrtf(red[0] + red[1] + red[2] + red[3]), 1e-12f);
  ((ushort4*)(Hf + (size_t)r * D))[t] = make_ushort4(
      f2h(x0 / nrm), f2h(x1 / nrm), f2h(x2 / nrm), f2h(x3 / nrm));
}

// ---------------------------------------------------------------- gemm_G
// G[i][j] = sum_k Wq[k][i] * Wk[k][j], stored f32 (exact path) + f16 (MFMA path).
__global__ void gemm_G(const float* __restrict__ Wq, const float* __restrict__ Wk,
                       float* __restrict__ Gf32, u16* __restrict__ Gf16) {
  __shared__ float Qs[32][64];
  __shared__ float Ks[32][64];
  const int t = threadIdx.x;
  const int i0 = blockIdx.x * 64, j0 = blockIdx.y * 64;
  const int tx = t & 15, ty = t >> 4;
  float acc[4][4] = {};
  for (int k0 = 0; k0 < D; k0 += 32) {
    #pragma unroll
    for (int q = 0; q < 2; ++q) {
      const int c = t + q * 256;
      const int row = c >> 4, c4 = (c & 15) << 2;
      *(float4*)&Qs[row][c4] = *(const float4*)&Wq[(size_t)(k0 + row) * D + i0 + c4];
      *(float4*)&Ks[row][c4] = *(const float4*)&Wk[(size_t)(k0 + row) * D + j0 + c4];
    }
    __syncthreads();
    #pragma unroll 8
    for (int kk = 0; kk < 32; ++kk) {
      const float4 qa = *(const float4*)&Qs[kk][tx << 2];
      const float4 kb = *(const float4*)&Ks[kk][ty << 2];
      const float qq[4] = {qa.x, qa.y, qa.z, qa.w};
      const float kv[4] = {kb.x, kb.y, kb.z, kb.w};
      #pragma unroll
      for (int a = 0; a < 4; ++a)
        #pragma unroll
        for (int bj = 0; bj < 4; ++bj) acc[a][bj] = fmaf(qq[a], kv[bj], acc[a][bj]);
    }
    __syncthreads();
  }
  #pragma unroll
  for (int a = 0; a < 4; ++a) {
    const int i = i0 + (tx << 2) + a;
    const size_t base = (size_t)i * D + j0 + (ty << 2);
    *(float4*)&Gf32[base] = make_float4(acc[a][0], acc[a][1], acc[a][2], acc[a][3]);
    *(ushort4*)&Gf16[base] = make_ushort4(
        f2h(acc[a][0]), f2h(acc[a][1]), f2h(acc[a][2]), f2h(acc[a][3]));
  }
}

// ---------------------------------------------------------------- gemm_main
// fp16 MFMA GEMM, counted-vmcnt pipelined (T3+T4+T5).
// BM=256 BN=128 BK=64, 512 thr (8 waves, 2 wr x 4 wc), per-wave 128x32 out.
// 3 LDS buffers, prefetch distance 2, s_waitcnt vmcnt(6) + raw barrier per tile.
// LDS rows 128B with XOR swizzle byte^=((row&7)<<4); staged via pre-swizzled
// global source + linear global_load_lds dest (both-sides rule).
// Fused epilogue: adj_part[nt][r] = sum_{i in tile} U[r,i]*Hf[r+1,i].
__global__ __launch_bounds__(512, 2) void gemm_main(
    const u16* __restrict__ Hf, const u16* __restrict__ Gf,
    float* __restrict__ adj_part) {
  __shared__ u16 AbufS[3][16384];     // 3 x 32KB  (256 rows x 64 k)
  __shared__ u16 BbufS[3][8192];      // 3 x 16KB  (128 rows x 64 k)
  __shared__ float adjp[4][256];

  const int tid = threadIdx.x;
  // XCD-aware bijective swizzle (1024 % 8 == 0)
  const int bid = blockIdx.x;
  const int swz = (bid & 7) * 128 + (bid >> 3);
  const int mt = swz >> 3, nt = swz & 7;
  const int r0 = mt << 8;             // 256-row block
  const int n0g = nt << 7;            // 128-col block

  const int wave = tid >> 6, lane = tid & 63;
  const int wr = wave >> 2;           // 0..1 -> rows wr*128
  const int wc = wave & 3;            // 0..3 -> cols wc*32
  const int frow = lane & 15;
  const int fgrp = lane >> 4;         // 0..3
  const int sw = (lane & 7) << 4;     // read-side swizzle mask (row&7 == lane&7)
  const int cb0 = (fgrp * 16) ^ sw;          // ks=0 frag byte col
  const int cb1 = (64 + fgrp * 16) ^ sw;     // ks=1 frag byte col
  const int Abase = (wr * 128 + frow) * 128; // bytes
  const int Bbase = (wc * 32 + frow) * 128;  // bytes

  // staging constants: thread covers row trow (per 64-row chunk), 16B at tcb
  const int trow = tid >> 3;                 // 0..63
  const int scb = ((tid & 7) << 4) ^ ((trow & 7) << 4);  // pre-swizzled src col
  const char* Asrc = (const char*)Hf + (size_t)(r0 + trow) * 2048 + scb;
  const char* Bsrc = (const char*)Gf + (size_t)(n0g + trow) * 2048 + scb;
  const int dst16 = tid * 16;

  f32x4 acc[8][2];
  #pragma unroll
  for (int m = 0; m < 8; ++m) { acc[m][0] = (f32x4){0,0,0,0}; acc[m][1] = (f32x4){0,0,0,0}; }

  auto stageA = [&](int b, int kt, int q) {
    gload_lds16(Asrc + (size_t)q * 131072 + (size_t)kt * 128,
                (char*)&AbufS[b][0] + q * 8192 + dst16);
  };
  auto stageB = [&](int b, int kt, int q) {
    gload_lds16(Bsrc + (size_t)q * 131072 + (size_t)kt * 128,
                (char*)&BbufS[b][0] + q * 8192 + dst16);
  };

  // tile body: 2 phases x 16 MFMA; stages for kt+2 interleaved when dostage
  auto do_tile = [&](int cur, int nb, int kt, bool dostage) {
    const char* Ab = (const char*)&AbufS[cur][0];
    const char* Bb = (const char*)&BbufS[cur][0];
    f16x8 b00 = *(const f16x8*)(Bb + Bbase + cb0);
    f16x8 b01 = *(const f16x8*)(Bb + Bbase + cb1);
    f16x8 b10 = *(const f16x8*)(Bb + Bbase + 2048 + cb0);
    f16x8 b11 = *(const f16x8*)(Bb + Bbase + 2048 + cb1);
    // phase 0: m 0..3
    {
      f16x8 a0k0 = *(const f16x8*)(Ab + Abase + 0 * 2048 + cb0);
      f16x8 a0k1 = *(const f16x8*)(Ab + Abase + 0 * 2048 + cb1);
      f16x8 a1k0 = *(const f16x8*)(Ab + Abase + 1 * 2048 + cb0);
      f16x8 a1k1 = *(const f16x8*)(Ab + Abase + 1 * 2048 + cb1);
      f16x8 a2k0 = *(const f16x8*)(Ab + Abase + 2 * 2048 + cb0);
      f16x8 a2k1 = *(const f16x8*)(Ab + Abase + 2 * 2048 + cb1);
      f16x8 a3k0 = *(const f16x8*)(Ab + Abase + 3 * 2048 + cb0);
      f16x8 a3k1 = *(const f16x8*)(Ab + Abase + 3 * 2048 + cb1);
      if (dostage) { stageA(nb, kt + 2, 0); stageA(nb, kt + 2, 1); stageA(nb, kt + 2, 2); }
      __builtin_amdgcn_s_setprio(1);
      acc[0][0] = __builtin_amdgcn_mfma_f32_16x16x32_f16(a0k0, b00, acc[0][0], 0, 0, 0);
      acc[0][0] = __builtin_amdgcn_mfma_f32_16x16x32_f16(a0k1, b01, acc[0][0], 0, 0, 0);
      acc[0][1] = __builtin_amdgcn_mfma_f32_16x16x32_f16(a0k0, b10, acc[0][1], 0, 0, 0);
      acc[0][1] = __builtin_amdgcn_mfma_f32_16x16x32_f16(a0k1, b11, acc[0][1], 0, 0, 0);
      acc[1][0] = __builtin_amdgcn_mfma_f32_16x16x32_f16(a1k0, b00, acc[1][0], 0, 0, 0);
      acc[1][0] = __builtin_amdgcn_mfma_f32_16x16x32_f16(a1k1, b01, acc[1][0], 0, 0, 0);
      acc[1][1] = __builtin_amdgcn_mfma_f32_16x16x32_f16(a1k0, b10, acc[1][1], 0, 0, 0);
      acc[1][1] = __builtin_amdgcn_mfma_f32_16x16x32_f16(a1k1, b11, acc[1][1], 0, 0, 0);
      acc[2][0] = __builtin_amdgcn_mfma_f32_16x16x32_f16(a2k0, b00, acc[2][0], 0, 0, 0);
      acc[2][0] = __builtin_amdgcn_mfma_f32_16x16x32_f16(a2k1, b01, acc[2][0], 0, 0, 0);
      acc[2][1] = __builtin_amdgcn_mfma_f32_16x16x32_f16(a2k0, b10, acc[2][1], 0, 0, 0);
      acc[2][1] = __builtin_amdgcn_mfma_f32_16x16x32_f16(a2k1, b11, acc[2][1], 0, 0, 0);
      acc[3][0] = __builtin_amdgcn_mfma_f32_16x16x32_f16(a3k0, b00, acc[3][0], 0, 0, 0);
      acc[3][0] = __builtin_amdgcn_mfma_f32_16x16x32_f16(a3k1, b01, acc[3][0], 0, 0, 0);
      acc[3][1] = __builtin_amdgcn_mfma_f32_16x16x32_f16(a3k0, b10, acc[3][1], 0, 0, 0);
      acc[3][1] = __builtin_amdgcn_mfma_f32_16x16x32_f16(a3k1, b11, acc[3][1], 0, 0, 0);
      __builtin_amdgcn_s_setprio(0);
    }
    // phase 1: m 4..7
    {
      f16x8 a4k0 = *(const f16x8*)(Ab + Abase + 4 * 2048 + cb0);
      f16x8 a4k1 = *(const f16x8*)(Ab + Abase + 4 * 2048 + cb1);
      f16x8 a5k0 = *(const f16x8*)(Ab + Abase + 5 * 2048 + cb0);
      f16x8 a5k1 = *(const f16x8*)(Ab + Abase + 5 * 2048 + cb1);
      f16x8 a6k0 = *(const f16x8*)(Ab + Abase + 6 * 2048 + cb0);
      f16x8 a6k1 = *(const f16x8*)(Ab + Abase + 6 * 2048 + cb1);
      f16x8 a7k0 = *(const f16x8*)(Ab + Abase + 7 * 2048 + cb0);
      f16x8 a7k1 = *(const f16x8*)(Ab + Abase + 7 * 2048 + cb1);
      if (dostage) { stageA(nb, kt + 2, 3); stageB(nb, kt + 2, 0); stageB(nb, kt + 2, 1); }
      __builtin_amdgcn_s_setprio(1);
      acc[4][0] = __builtin_amdgcn_mfma_f32_16x16x32_f16(a4k0, b00, acc[4][0], 0, 0, 0);
      acc[4][0] = __builtin_amdgcn_mfma_f32_16x16x32_f16(a4k1, b01, acc[4][0], 0, 0, 0);
      acc[4][1] = __builtin_amdgcn_mfma_f32_16x16x32_f16(a4k0, b10, acc[4][1], 0, 0, 0);
      acc[4][1] = __builtin_amdgcn_mfma_f32_16x16x32_f16(a4k1, b11, acc[4][1], 0, 0, 0);
      acc[5][0] = __builtin_amdgcn_mfma_f32_16x16x32_f16(a5k0, b00, acc[5][0], 0, 0, 0);
      acc[5][0] = __builtin_amdgcn_mfma_f32_16x16x32_f16(a5k1, b01, acc[5][0], 0, 0, 0);
      acc[5][1] = __builtin_amdgcn_mfma_f32_16x16x32_f16(a5k0, b10, acc[5][1], 0, 0, 0);
      acc[5][1] = __builtin_amdgcn_mfma_f32_16x16x32_f16(a5k1, b11, acc[5][1], 0, 0, 0);
      acc[6][0] = __builtin_amdgcn_mfma_f32_16x16x32_f16(a6k0, b00, acc[6][0], 0, 0, 0);
      acc[6][0] = __builtin_amdgcn_mfma_f32_16x16x32_f16(a6k1, b01, acc[6][0], 0, 0, 0);
      acc[6][1] = __builtin_amdgcn_mfma_f32_16x16x32_f16(a6k0, b10, acc[6][1], 0, 0, 0);
      acc[6][1] = __builtin_amdgcn_mfma_f32_16x16x32_f16(a6k1, b11, acc[6][1], 0, 0, 0);
      acc[7][0] = __builtin_amdgcn_mfma_f32_16x16x32_f16(a7k0, b00, acc[7][0], 0, 0, 0);
      acc[7][0] = __builtin_amdgcn_mfma_f32_16x16x32_f16(a7k1, b01, acc[7][0], 0, 0, 0);
      acc[7][1] = __builtin_amdgcn_mfma_f32_16x16x32_f16(a7k0, b10, acc[7][1], 0, 0, 0);
      acc[7][1] = __builtin_amdgcn_mfma_f32_16x16x32_f16(a7k1, b11, acc[7][1], 0, 0, 0);
      __builtin_amdgcn_s_setprio(0);
    }
  };

  // prologue: stage tiles 0 and 1 (6 loads each)
  stageA(0, 0, 0); stageA(0, 0, 1); stageA(0, 0, 2); stageA(0, 0, 3);
  stageB(0, 0, 0); stageB(0, 0, 1);
  stageA(1, 1, 0); stageA(1, 1, 1); stageA(1, 1, 2); stageA(1, 1, 3);
  stageB(1, 1, 0); stageB(1, 1, 1);

  int cur = 0;
  #pragma unroll 1
  for (int kt = 0; kt < 14; ++kt) {
    const int nb = (cur >= 1) ? cur - 1 : 2;   // (cur+2)%3
    VMCNT(6);
    __builtin_amdgcn_s_barrier();
    __builtin_amdgcn_sched_barrier(0);
    do_tile(cur, nb, kt, true);
    cur = (cur == 2) ? 0 : cur + 1;
  }
  // kt = 14 (no stage)
  VMCNT(6);
  __builtin_amdgcn_s_barrier();
  __builtin_amdgcn_sched_barrier(0);
  do_tile(cur, 0, 14, false);
  cur = (cur == 2) ? 0 : cur + 1;
  // kt = 15 (no stage, full drain)
  VMCNT(0);
  __builtin_amdgcn_s_barrier();
  __builtin_amdgcn_sched_barrier(0);
  do_tile(cur, 0, 15, false);

  // epilogue: rowwise dot with shifted h (f16->f32), reduce over 16 lanes
  #pragma unroll
  for (int m = 0; m < 8; ++m) {
    #pragma unroll
    for (int reg = 0; reg < 4; ++reg) {
      const int rl = wr * 128 + m * 16 + fgrp * 4 + reg;
      const int gr = r0 + rl;
      float sum = 0.f;
      if (((gr + 1) & (S - 1)) != 0) {
        const u16* hrow = Hf + (size_t)(gr + 1) * D + n0g + wc * 32 + frow;
        sum = acc[m][0][reg] * h2f(hrow[0]) + acc[m][1][reg] * h2f(hrow[16]);
      }
      #pragma unroll
      for (int off = 1; off < 16; off <<= 1) sum += __shfl_xor(sum, off, 64);
      if (frow == 0) adjp[wc][rl] = sum;
    }
  }
  __syncthreads();
  if (tid < 256) {
    adj_part[(size_t)nt * BS + r0 + tid] =
        adjp[0][tid] + adjp[1][tid] + adjp[2][tid] + adjp[3][tid];
  }
}

// ---------------------------------------------------------------- score_flag
// score -> decision logit z -> hard bit; flag near-threshold positions.
__global__ void score_flag(const float* __restrict__ adj_part,
                           const float* __restrict__ sig_temp, const float* __restrict__ sig_thr,
                           const float* __restrict__ noise_u,
                           unsigned char* __restrict__ hard, int* __restrict__ flags,
                           int* __restrict__ fcnt) {
  const int idx = blockIdx.x * 256 + threadIdx.x;   // position b*S + s
  const int s = idx & (S - 1);
  float sc = 0.f;
  if (s > 0) {
    float a = 0.f;
    #pragma unroll
    for (int p = 0; p < 8; ++p) a += adj_part[(size_t)p * BS + idx - 1];
    sc = a * SCALE;
  }
  const float temp = sig_temp[0], thr = sig_thr[0];
  float pr = 1.f / (1.f + expf(-(sc - thr) / temp));
  pr = fminf(fmaxf(pr, 0.f), 1.f);
  if (s == 0) pr = 1.f;
  const float p = fminf(fmaxf(pr, FEPS), 1.f - FEPS);
  const float lgt = logf(p) - log1pf(-p);
  const float uu = fminf(fmaxf(noise_u[idx], FEPS), 1.f - FEPS);
  const float lgs = logf(uu) - log1pf(-uu);
  const float z = lgt + lgs;                        // soft > 0.5 <=> z > 0
  hard[idx] = (z > 0.f) ? 1 : 0;
  if (s > 0 && fabsf(z) < 1e-3f) {                  // margin >> fp16 score error
    const int k = atomicAdd(fcnt, 1);
    if (k < BS) flags[k] = idx;
  }
}

// ---------------------------------------------------------------- fixup
// Exact f32 recompute of flagged decisions: adj = h[idx]' * G * h[idx-1].
__global__ __launch_bounds__(256) void fixup(const int* __restrict__ flags,
    const int* __restrict__ fcnt, const float* __restrict__ hidden,
    const float* __restrict__ pos, const float* __restrict__ Gf32,
    const float* __restrict__ sig_temp, const float* __restrict__ sig_thr,
    const float* __restrict__ noise_u, unsigned char* __restrict__ hard) {
  __shared__ float h0[1024];
  __shared__ float h1[1024];
  __shared__ float red[4];
  const int t = threadIdx.x;
  const int nf = min(*fcnt, BS);
  for (int w = blockIdx.x; w < nf; w += gridDim.x) {
    const int idx = flags[w];
    #pragma unroll
    for (int rr = 0; rr < 2; ++rr) {
      const int r = idx - 1 + rr;
      float* hs = rr ? h1 : h0;
      const float4 hv = ((const float4*)(hidden + (size_t)r * D))[t];
      const float4 pv = ((const float4*)(pos + (size_t)(r & (S - 1)) * D))[t];
      const float x0 = hv.x + pv.x, x1 = hv.y + pv.y, x2 = hv.z + pv.z, x3 = hv.w + pv.w;
      float ss = x0 * x0 + x1 * x1 + x2 * x2 + x3 * x3;
      #pragma unroll
      for (int m = 1; m < 64; m <<= 1) ss += __shfl_xor(ss, m, 64);
      __syncthreads();                       // protect red from previous use
      if ((t & 63) == 0) red[t >> 6] = ss;
      __syncthreads();
      const float nrm = fmaxf(sqrtf(red[0] + red[1] + red[2] + red[3]), 1e-12f);
      hs[4 * t + 0] = x0 / nrm; hs[4 * t + 1] = x1 / nrm;
      hs[4 * t + 2] = x2 / nrm; hs[4 * t + 3] = x3 / nrm;
    }
    __syncthreads();
    float acc = 0.f;
    #pragma unroll
    for (int ii = 0; ii < 4; ++ii) {
      const int i = t + (ii << 8);
      float ti = 0.f;
      for (int j = 0; j < 1024; ++j) ti = fmaf(Gf32[(size_t)i * D + j], h0[j], ti);
      acc = fmaf(h1[i], ti, acc);
    }
    #pragma unroll
    for (int m = 1; m < 64; m <<= 1) acc += __shfl_xor(acc, m, 64);
    __syncthreads();
    if ((t & 63) == 0) red[t >> 6] = acc;
    __syncthreads();
    if (t == 0) {
      const float sc = (red[0] + red[1] + red[2] + red[3]) * SCALE;
      const float temp = sig_temp[0], thr = sig_thr[0];
      float pr = 1.f / (1.f + expf(-(sc - thr) / temp));
      pr = fminf(fmaxf(pr, 0.f), 1.f);
      const float p = fminf(fmaxf(pr, FEPS), 1.f - FEPS);
      const float lgt = logf(p) - log1pf(-p);
      const float uu = fminf(fmaxf(noise_u[idx], FEPS), 1.f - FEPS);
      const float lgs = logf(uu) - log1pf(-uu);
      hard[idx] = ((lgt + lgs) > 0.f) ? 1 : 0;
    }
    __syncthreads();
  }
}

// ---------------------------------------------------------------- decide_scan
// hard bits -> per-batch cumsum -> segment starts (no transcendentals).
__global__ void decide_scan(const unsigned char* __restrict__ hard_,
                            int* __restrict__ seg_start, int* __restrict__ nseg_out,
                            float* __restrict__ kf_out) {
  const int b = blockIdx.x, t = threadIdx.x;
  __shared__ int ssum[256];
  const uint4 hv = ((const uint4*)(hard_ + (size_t)b * S))[t];
  const uint32_t wds[4] = {hv.x, hv.y, hv.z, hv.w};
  const uint32_t bsum = hv.x + hv.y + hv.z + hv.w;     // bytewise (each <=1)
  const int loc = (int)((bsum & 255) + ((bsum >> 8) & 255) +
                        ((bsum >> 16) & 255) + (bsum >> 24));
  ssum[t] = loc;
  __syncthreads();
  for (int off = 1; off < 256; off <<= 1) {
    int v = ssum[t];
    if (t >= off) v += ssum[t - off];
    __syncthreads();
    ssum[t] = v;
    __syncthreads();
  }
  const int ktot = ssum[255];
  int cum = ssum[t] - loc;                 // exclusive prefix
  #pragma unroll
  for (int e = 0; e < 16; ++e) {
    const int s = (t << 4) + e;
    const int bit = (int)((wds[e >> 2] >> ((e & 3) * 8)) & 1);
    const int pseg = min(max(cum - 1, 0), S - 1);
    cum += bit;
    const int seg = min(max(cum - 1, 0), S - 1);
    if (s == 0 || seg != pseg) seg_start[b * S + seg] = s;
  }
  if (t == 0) {
    nseg_out[b] = min(max(ktot, 1), S);
    kf_out[b] = (float)ktot;
  }
}

// ---------------------------------------------------------------- pool
// out[j, b, :] = mean over segment j of h rows (f16->f32), zeros for j >= nseg.
__global__ void pool(const u16* __restrict__ Hf,
                     const int* __restrict__ seg_start, const int* __restrict__ nseg_arr,
                     float* __restrict__ out) {
  const int j = blockIdx.x, b = blockIdx.y, t = threadIdx.x;
  const int ns = nseg_arr[b];
  float4* o = (float4*)(out + (((size_t)j * Bb + b) << 10));
  if (j >= ns) {
    o[t] = (float4){0.f, 0.f, 0.f, 0.f};
    return;
  }
  const int s0 = seg_start[b * S + j];
  const int s1 = (j + 1 < ns) ? seg_start[b * S + j + 1] : S;
  float a0 = 0.f, a1 = 0.f, a2 = 0.f, a3 = 0.f;
  for (int s = s0; s < s1; ++s) {
    const ushort4 hv = *(const ushort4*)(Hf + (((size_t)b * S + s) << 10) + (t << 2));
    a0 += h2f(hv.x); a1 += h2f(hv.y); a2 += h2f(hv.z); a3 += h2f(hv.w);
  }
  const float c = (float)(s1 - s0);
  o[t] = (float4){a0 / c, a1 / c, a2 / c, a3 / c};
}

// ---------------------------------------------------------------- loss
__global__ void loss_k(const float* __restrict__ kf, float* __restrict__ out) {
  const int t = threadIdx.x;
  float lp = 0.f;
  if (t < 8) {
    const float n = 4096.f;
    const float k = kf[t];
    lp = lgammaf(n + 1.f) - lgammaf(k + 1.f) - lgammaf(n - k + 1.f)
       + k * logf(0.2f) + (n - k) * log1pf(-0.2f);
  }
  #pragma unroll
  for (int off = 1; off < 8; off <<= 1) lp += __shfl_xor(lp, off, 64);
  if (t == 0) out[(size_t)BS * 1024] = -(lp / 8.f) / 4096.f;
}

}  // namespace

extern "C" void kernel_launch(void* const* d_in, const int* in_sizes, int n_in,
                              void* d_out, int out_size, void* d_ws, size_t ws_size,
                              hipStream_t stream) {
  (void)in_sizes; (void)n_in; (void)out_size; (void)ws_size;
  const float* hidden = (const float*)d_in[0];
  const float* pos    = (const float*)d_in[1];
  const float* Wq     = (const float*)d_in[2];
  const float* Wk     = (const float*)d_in[3];
  const float* stemp  = (const float*)d_in[4];
  const float* sthr   = (const float*)d_in[5];
  const float* nois   = (const float*)d_in[6];
  float* out = (float*)d_out;
  char* ws = (char*)d_ws;

  // workspace layout (bytes)
  u16*   Hf        = (u16*)(ws);                       // 67,108,864 (f16 bits)
  u16*   Gf16      = (u16*)(ws + 67108864);            //  2,097,152
  float* Gf32      = (float*)(ws + 69206016);          //  4,194,304
  float* adj_part  = (float*)(ws + 73400320);          //  1,048,576 (8 x BS f32)
  unsigned char* hard = (unsigned char*)(ws + 74448896); //   32,768
  int*   flags     = (int*)(ws + 74481664);            //    131,072
  int*   fcnt      = (int*)(ws + 74612736);            //         64
  int*   seg_start = (int*)(ws + 74612800);            //    131,072
  int*   nseg      = (int*)(ws + 74743872);            //         64
  float* kf        = (float*)(ws + 74743936);          //         32

  hipLaunchKernelGGL(prep_h,      dim3(BS),      dim3(256), 0, stream, hidden, pos, Hf, fcnt);
  hipLaunchKernelGGL(gemm_G,      dim3(16, 16),  dim3(256), 0, stream, Wq, Wk, Gf32, Gf16);
  hipLaunchKernelGGL(gemm_main,   dim3(1024),    dim3(512), 0, stream, Hf, Gf16, adj_part);
  hipLaunchKernelGGL(score_flag,  dim3(BS/256),  dim3(256), 0, stream, adj_part, stemp, sthr, nois, hard, flags, fcnt);
  hipLaunchKernelGGL(fixup,       dim3(64),      dim3(256), 0, stream, flags, fcnt, hidden, pos, Gf32, stemp, sthr, nois, hard);
  hipLaunchKernelGGL(decide_scan, dim3(Bb),      dim3(256), 0, stream, hard, seg_start, nseg, kf);
  hipLaunchKernelGGL(pool,        dim3(S, Bb),   dim3(256), 0, stream, Hf, seg_start, nseg, out);
  hipLaunchKernelGGL(loss_k,      dim3(1),       dim3(64),  0, stream, kf, out);
}

// Round 4
// 278.798 us; speedup vs baseline: 1.7646x; 1.3687x over previous
//
#include <hip/hip_runtime.h>
#include <stdint.h>

namespace {

constexpr int Bb = 8, S = 4096, D = 1024, BS = 32768;
constexpr float SCALE = 0.08838834764831845f;           // (D/NUM_HEADS)^-0.5
constexpr float FEPS  = 1.1920928955078125e-07f;        // float32 eps (2^-23)
constexpr int MAXF = 4096;                              // max rescued items

typedef unsigned short u16;
typedef __attribute__((ext_vector_type(8))) _Float16 f16x8;
typedef __attribute__((ext_vector_type(4))) float    f32x4;

__device__ __forceinline__ u16 f2h(float f) {
  _Float16 h = (_Float16)f;
  return __builtin_bit_cast(u16, h);
}
__device__ __forceinline__ float h2f(u16 u) {
  return (float)__builtin_bit_cast(_Float16, u);
}
__device__ __forceinline__ void gload_lds16(const void* g, void* l) {
  __builtin_amdgcn_global_load_lds((const __attribute__((address_space(1))) void*)g,
                                   (__attribute__((address_space(3))) void*)l, 16, 0, 0);
}
#define VMCNT(n) asm volatile("s_waitcnt vmcnt(" #n ")" ::: "memory")

// ---------------------------------------------------------------- prep_h
// h = (hidden + pos) / max(||.||2, 1e-12), stored f16. Also zeroes fcnt.
__global__ void prep_h(const float* __restrict__ hidden, const float* __restrict__ pos,
                       u16* __restrict__ Hf, int* __restrict__ fcnt) {
  if (blockIdx.x == 0 && threadIdx.x == 0) *fcnt = 0;
  const int r = blockIdx.x;          // row in [0, BS)
  const int t = threadIdx.x;         // 256 threads, 4 elems each
  const float4 hv = ((const float4*)(hidden + (size_t)r * D))[t];
  const float4 pv = ((const float4*)(pos + (size_t)(r & (S - 1)) * D))[t];
  float x0 = hv.x + pv.x, x1 = hv.y + pv.y, x2 = hv.z + pv.z, x3 = hv.w + pv.w;
  float ss = x0 * x0 + x1 * x1 + x2 * x2 + x3 * x3;
  #pragma unroll
  for (int m = 1; m < 64; m <<= 1) ss += __shfl_xor(ss, m, 64);
  __shared__ float red[4];
  if ((t & 63) == 0) red[t >> 6] = ss;
  __syncthreads();
  const float nrm = fmaxf(sqrtf(red[0] + red[1] + red[2] + red[3]), 1e-12f);
  ((ushort4*)(Hf + (size_t)r * D))[t] = make_ushort4(
      f2h(x0 / nrm), f2h(x1 / nrm), f2h(x2 / nrm), f2h(x3 / nrm));
}

// ---------------------------------------------------------------- gemm_G
// G[i][j] = sum_k Wq[k][i] * Wk[k][j], stored f32 (exact path) + f16 (MFMA path).
__global__ void gemm_G(const float* __restrict__ Wq, const float* __restrict__ Wk,
                       float* __restrict__ Gf32, u16* __restrict__ Gf16) {
  __shared__ float Qs[32][64];
  __shared__ float Ks[32][64];
  const int t = threadIdx.x;
  const int i0 = blockIdx.x * 64, j0 = blockIdx.y * 64;
  const int tx = t & 15, ty = t >> 4;
  float acc[4][4] = {};
  for (int k0 = 0; k0 < D; k0 += 32) {
    #pragma unroll
    for (int q = 0; q < 2; ++q) {
      const int c = t + q * 256;
      const int row = c >> 4, c4 = (c & 15) << 2;
      *(float4*)&Qs[row][c4] = *(const float4*)&Wq[(size_t)(k0 + row) * D + i0 + c4];
      *(float4*)&Ks[row][c4] = *(const float4*)&Wk[(size_t)(k0 + row) * D + j0 + c4];
    }
    __syncthreads();
    #pragma unroll 8
    for (int kk = 0; kk < 32; ++kk) {
      const float4 qa = *(const float4*)&Qs[kk][tx << 2];
      const float4 kb = *(const float4*)&Ks[kk][ty << 2];
      const float qq[4] = {qa.x, qa.y, qa.z, qa.w};
      const float kv[4] = {kb.x, kb.y, kb.z, kb.w};
      #pragma unroll
      for (int a = 0; a < 4; ++a)
        #pragma unroll
        for (int bj = 0; bj < 4; ++bj) acc[a][bj] = fmaf(qq[a], kv[bj], acc[a][bj]);
    }
    __syncthreads();
  }
  #pragma unroll
  for (int a = 0; a < 4; ++a) {
    const int i = i0 + (tx << 2) + a;
    const size_t base = (size_t)i * D + j0 + (ty << 2);
    *(float4*)&Gf32[base] = make_float4(acc[a][0], acc[a][1], acc[a][2], acc[a][3]);
    *(ushort4*)&Gf16[base] = make_ushort4(
        f2h(acc[a][0]), f2h(acc[a][1]), f2h(acc[a][2]), f2h(acc[a][3]));
  }
}

// ---------------------------------------------------------------- gemm_main
// fp16 MFMA GEMM, counted-vmcnt pipelined (T3+T4+T5).
// BM=256 BN=128 BK=64, 512 thr (8 waves, 2 wr x 4 wc), per-wave 128x32 out.
// 3 LDS buffers, prefetch distance 2, s_waitcnt vmcnt(6) + raw barrier per tile.
__global__ __launch_bounds__(512, 2) void gemm_main(
    const u16* __restrict__ Hf, const u16* __restrict__ Gf,
    float* __restrict__ adj_part) {
  __shared__ u16 AbufS[3][16384];     // 3 x 32KB  (256 rows x 64 k)
  __shared__ u16 BbufS[3][8192];      // 3 x 16KB  (128 rows x 64 k)
  __shared__ float adjp[4][256];

  const int tid = threadIdx.x;
  const int bid = blockIdx.x;
  const int swz = (bid & 7) * 128 + (bid >> 3);
  const int mt = swz >> 3, nt = swz & 7;
  const int r0 = mt << 8;             // 256-row block
  const int n0g = nt << 7;            // 128-col block

  const int wave = tid >> 6, lane = tid & 63;
  const int wr = wave >> 2;           // 0..1 -> rows wr*128
  const int wc = wave & 3;            // 0..3 -> cols wc*32
  const int frow = lane & 15;
  const int fgrp = lane >> 4;         // 0..3
  const int sw = (lane & 7) << 4;     // read-side swizzle mask (row&7 == lane&7)
  const int cb0 = (fgrp * 16) ^ sw;          // ks=0 frag byte col
  const int cb1 = (64 + fgrp * 16) ^ sw;     // ks=1 frag byte col
  const int Abase = (wr * 128 + frow) * 128; // bytes
  const int Bbase = (wc * 32 + frow) * 128;  // bytes

  const int trow = tid >> 3;                 // 0..63
  const int scb = ((tid & 7) << 4) ^ ((trow & 7) << 4);  // pre-swizzled src col
  const char* Asrc = (const char*)Hf + (size_t)(r0 + trow) * 2048 + scb;
  const char* Bsrc = (const char*)Gf + (size_t)(n0g + trow) * 2048 + scb;
  const int dst16 = tid * 16;

  f32x4 acc[8][2];
  #pragma unroll
  for (int m = 0; m < 8; ++m) { acc[m][0] = (f32x4){0,0,0,0}; acc[m][1] = (f32x4){0,0,0,0}; }

  auto stageA = [&](int b, int kt, int q) {
    gload_lds16(Asrc + (size_t)q * 131072 + (size_t)kt * 128,
                (char*)&AbufS[b][0] + q * 8192 + dst16);
  };
  auto stageB = [&](int b, int kt, int q) {
    gload_lds16(Bsrc + (size_t)q * 131072 + (size_t)kt * 128,
                (char*)&BbufS[b][0] + q * 8192 + dst16);
  };

  auto do_tile = [&](int cur, int nb, int kt, bool dostage) {
    const char* Ab = (const char*)&AbufS[cur][0];
    const char* Bb = (const char*)&BbufS[cur][0];
    f16x8 b00 = *(const f16x8*)(Bb + Bbase + cb0);
    f16x8 b01 = *(const f16x8*)(Bb + Bbase + cb1);
    f16x8 b10 = *(const f16x8*)(Bb + Bbase + 2048 + cb0);
    f16x8 b11 = *(const f16x8*)(Bb + Bbase + 2048 + cb1);
    {
      f16x8 a0k0 = *(const f16x8*)(Ab + Abase + 0 * 2048 + cb0);
      f16x8 a0k1 = *(const f16x8*)(Ab + Abase + 0 * 2048 + cb1);
      f16x8 a1k0 = *(const f16x8*)(Ab + Abase + 1 * 2048 + cb0);
      f16x8 a1k1 = *(const f16x8*)(Ab + Abase + 1 * 2048 + cb1);
      f16x8 a2k0 = *(const f16x8*)(Ab + Abase + 2 * 2048 + cb0);
      f16x8 a2k1 = *(const f16x8*)(Ab + Abase + 2 * 2048 + cb1);
      f16x8 a3k0 = *(const f16x8*)(Ab + Abase + 3 * 2048 + cb0);
      f16x8 a3k1 = *(const f16x8*)(Ab + Abase + 3 * 2048 + cb1);
      if (dostage) { stageA(nb, kt + 2, 0); stageA(nb, kt + 2, 1); stageA(nb, kt + 2, 2); }
      __builtin_amdgcn_s_setprio(1);
      acc[0][0] = __builtin_amdgcn_mfma_f32_16x16x32_f16(a0k0, b00, acc[0][0], 0, 0, 0);
      acc[0][0] = __builtin_amdgcn_mfma_f32_16x16x32_f16(a0k1, b01, acc[0][0], 0, 0, 0);
      acc[0][1] = __builtin_amdgcn_mfma_f32_16x16x32_f16(a0k0, b10, acc[0][1], 0, 0, 0);
      acc[0][1] = __builtin_amdgcn_mfma_f32_16x16x32_f16(a0k1, b11, acc[0][1], 0, 0, 0);
      acc[1][0] = __builtin_amdgcn_mfma_f32_16x16x32_f16(a1k0, b00, acc[1][0], 0, 0, 0);
      acc[1][0] = __builtin_amdgcn_mfma_f32_16x16x32_f16(a1k1, b01, acc[1][0], 0, 0, 0);
      acc[1][1] = __builtin_amdgcn_mfma_f32_16x16x32_f16(a1k0, b10, acc[1][1], 0, 0, 0);
      acc[1][1] = __builtin_amdgcn_mfma_f32_16x16x32_f16(a1k1, b11, acc[1][1], 0, 0, 0);
      acc[2][0] = __builtin_amdgcn_mfma_f32_16x16x32_f16(a2k0, b00, acc[2][0], 0, 0, 0);
      acc[2][0] = __builtin_amdgcn_mfma_f32_16x16x32_f16(a2k1, b01, acc[2][0], 0, 0, 0);
      acc[2][1] = __builtin_amdgcn_mfma_f32_16x16x32_f16(a2k0, b10, acc[2][1], 0, 0, 0);
      acc[2][1] = __builtin_amdgcn_mfma_f32_16x16x32_f16(a2k1, b11, acc[2][1], 0, 0, 0);
      acc[3][0] = __builtin_amdgcn_mfma_f32_16x16x32_f16(a3k0, b00, acc[3][0], 0, 0, 0);
      acc[3][0] = __builtin_amdgcn_mfma_f32_16x16x32_f16(a3k1, b01, acc[3][0], 0, 0, 0);
      acc[3][1] = __builtin_amdgcn_mfma_f32_16x16x32_f16(a3k0, b10, acc[3][1], 0, 0, 0);
      acc[3][1] = __builtin_amdgcn_mfma_f32_16x16x32_f16(a3k1, b11, acc[3][1], 0, 0, 0);
      __builtin_amdgcn_s_setprio(0);
    }
    {
      f16x8 a4k0 = *(const f16x8*)(Ab + Abase + 4 * 2048 + cb0);
      f16x8 a4k1 = *(const f16x8*)(Ab + Abase + 4 * 2048 + cb1);
      f16x8 a5k0 = *(const f16x8*)(Ab + Abase + 5 * 2048 + cb0);
      f16x8 a5k1 = *(const f16x8*)(Ab + Abase + 5 * 2048 + cb1);
      f16x8 a6k0 = *(const f16x8*)(Ab + Abase + 6 * 2048 + cb0);
      f16x8 a6k1 = *(const f16x8*)(Ab + Abase + 6 * 2048 + cb1);
      f16x8 a7k0 = *(const f16x8*)(Ab + Abase + 7 * 2048 + cb0);
      f16x8 a7k1 = *(const f16x8*)(Ab + Abase + 7 * 2048 + cb1);
      if (dostage) { stageA(nb, kt + 2, 3); stageB(nb, kt + 2, 0); stageB(nb, kt + 2, 1); }
      __builtin_amdgcn_s_setprio(1);
      acc[4][0] = __builtin_amdgcn_mfma_f32_16x16x32_f16(a4k0, b00, acc[4][0], 0, 0, 0);
      acc[4][0] = __builtin_amdgcn_mfma_f32_16x16x32_f16(a4k1, b01, acc[4][0], 0, 0, 0);
      acc[4][1] = __builtin_amdgcn_mfma_f32_16x16x32_f16(a4k0, b10, acc[4][1], 0, 0, 0);
      acc[4][1] = __builtin_amdgcn_mfma_f32_16x16x32_f16(a4k1, b11, acc[4][1], 0, 0, 0);
      acc[5][0] = __builtin_amdgcn_mfma_f32_16x16x32_f16(a5k0, b00, acc[5][0], 0, 0, 0);
      acc[5][0] = __builtin_amdgcn_mfma_f32_16x16x32_f16(a5k1, b01, acc[5][0], 0, 0, 0);
      acc[5][1] = __builtin_amdgcn_mfma_f32_16x16x32_f16(a5k0, b10, acc[5][1], 0, 0, 0);
      acc[5][1] = __builtin_amdgcn_mfma_f32_16x16x32_f16(a5k1, b11, acc[5][1], 0, 0, 0);
      acc[6][0] = __builtin_amdgcn_mfma_f32_16x16x32_f16(a6k0, b00, acc[6][0], 0, 0, 0);
      acc[6][0] = __builtin_amdgcn_mfma_f32_16x16x32_f16(a6k1, b01, acc[6][0], 0, 0, 0);
      acc[6][1] = __builtin_amdgcn_mfma_f32_16x16x32_f16(a6k0, b10, acc[6][1], 0, 0, 0);
      acc[6][1] = __builtin_amdgcn_mfma_f32_16x16x32_f16(a6k1, b11, acc[6][1], 0, 0, 0);
      acc[7][0] = __builtin_amdgcn_mfma_f32_16x16x32_f16(a7k0, b00, acc[7][0], 0, 0, 0);
      acc[7][0] = __builtin_amdgcn_mfma_f32_16x16x32_f16(a7k1, b01, acc[7][0], 0, 0, 0);
      acc[7][1] = __builtin_amdgcn_mfma_f32_16x16x32_f16(a7k0, b10, acc[7][1], 0, 0, 0);
      acc[7][1] = __builtin_amdgcn_mfma_f32_16x16x32_f16(a7k1, b11, acc[7][1], 0, 0, 0);
      __builtin_amdgcn_s_setprio(0);
    }
  };

  stageA(0, 0, 0); stageA(0, 0, 1); stageA(0, 0, 2); stageA(0, 0, 3);
  stageB(0, 0, 0); stageB(0, 0, 1);
  stageA(1, 1, 0); stageA(1, 1, 1); stageA(1, 1, 2); stageA(1, 1, 3);
  stageB(1, 1, 0); stageB(1, 1, 1);

  int cur = 0;
  #pragma unroll 1
  for (int kt = 0; kt < 14; ++kt) {
    const int nb = (cur >= 1) ? cur - 1 : 2;   // (cur+2)%3
    VMCNT(6);
    __builtin_amdgcn_s_barrier();
    __builtin_amdgcn_sched_barrier(0);
    do_tile(cur, nb, kt, true);
    cur = (cur == 2) ? 0 : cur + 1;
  }
  VMCNT(6);
  __builtin_amdgcn_s_barrier();
  __builtin_amdgcn_sched_barrier(0);
  do_tile(cur, 0, 14, false);
  cur = (cur == 2) ? 0 : cur + 1;
  VMCNT(0);
  __builtin_amdgcn_s_barrier();
  __builtin_amdgcn_sched_barrier(0);
  do_tile(cur, 0, 15, false);

  // epilogue: rowwise dot with shifted h (f16->f32), reduce over 16 lanes
  #pragma unroll
  for (int m = 0; m < 8; ++m) {
    #pragma unroll
    for (int reg = 0; reg < 4; ++reg) {
      const int rl = wr * 128 + m * 16 + fgrp * 4 + reg;
      const int gr = r0 + rl;
      float sum = 0.f;
      if (((gr + 1) & (S - 1)) != 0) {
        const u16* hrow = Hf + (size_t)(gr + 1) * D + n0g + wc * 32 + frow;
        sum = acc[m][0][reg] * h2f(hrow[0]) + acc[m][1][reg] * h2f(hrow[16]);
      }
      #pragma unroll
      for (int off = 1; off < 16; off <<= 1) sum += __shfl_xor(sum, off, 64);
      if (frow == 0) adjp[wc][rl] = sum;
    }
  }
  __syncthreads();
  if (tid < 256) {
    adj_part[(size_t)nt * BS + r0 + tid] =
        adjp[0][tid] + adjp[1][tid] + adjp[2][tid] + adjp[3][tid];
  }
}

// ---------------------------------------------------------------- score_flag
// score -> decision logit z -> hard bit; flag near-threshold positions.
__global__ void score_flag(const float* __restrict__ adj_part,
                           const float* __restrict__ sig_temp, const float* __restrict__ sig_thr,
                           const float* __restrict__ noise_u,
                           unsigned char* __restrict__ hard, int* __restrict__ flags,
                           int* __restrict__ fcnt) {
  const int idx = blockIdx.x * 256 + threadIdx.x;   // position b*S + s
  const int s = idx & (S - 1);
  float sc = 0.f;
  if (s > 0) {
    float a = 0.f;
    #pragma unroll
    for (int p = 0; p < 8; ++p) a += adj_part[(size_t)p * BS + idx - 1];
    sc = a * SCALE;
  }
  const float temp = sig_temp[0], thr = sig_thr[0];
  float pr = 1.f / (1.f + expf(-(sc - thr) / temp));
  pr = fminf(fmaxf(pr, 0.f), 1.f);
  if (s == 0) pr = 1.f;
  const float p = fminf(fmaxf(pr, FEPS), 1.f - FEPS);
  const float lgt = logf(p) - log1pf(-p);
  const float uu = fminf(fmaxf(noise_u[idx], FEPS), 1.f - FEPS);
  const float lgs = logf(uu) - log1pf(-uu);
  const float z = lgt + lgs;                        // soft > 0.5 <=> z > 0
  hard[idx] = (z > 0.f) ? 1 : 0;
  if (s > 0 && fabsf(z) < 1e-3f) {                  // margin >> fp16 score error
    const int k = atomicAdd(fcnt, 1);
    if (k < MAXF) flags[k] = idx;
  }
}

// ---------------------------------------------------------------- fixup_part
// Exact f32 partial scores for flagged items. Block = (item-slot, slice);
// slice covers 128 rows of G. Coalesced float4 loads; deterministic block
// reduce -> pz[item][slice]. 256 blocks = 32 item-slots x 8 slices.
__global__ __launch_bounds__(256) void fixup_part(const int* __restrict__ flags,
    const int* __restrict__ fcnt, const float* __restrict__ hidden,
    const float* __restrict__ pos, const float* __restrict__ Gf32,
    float* __restrict__ pz) {
  __shared__ float h0s[1024];
  __shared__ float h1s[1024];
  __shared__ float red[4];
  const int t = threadIdx.x;
  const int slice = blockIdx.x & 7;
  const int nf = min(*fcnt, MAXF);
  for (int w = blockIdx.x >> 3; w < nf; w += 32) {
    const int idx = flags[w];
    #pragma unroll
    for (int rr = 0; rr < 2; ++rr) {
      const int r = idx - 1 + rr;
      float* hs = rr ? h1s : h0s;
      const float4 hv = ((const float4*)(hidden + (size_t)r * D))[t];
      const float4 pv = ((const float4*)(pos + (size_t)(r & (S - 1)) * D))[t];
      const float x0 = hv.x + pv.x, x1 = hv.y + pv.y, x2 = hv.z + pv.z, x3 = hv.w + pv.w;
      float ss = x0 * x0 + x1 * x1 + x2 * x2 + x3 * x3;
      #pragma unroll
      for (int m = 1; m < 64; m <<= 1) ss += __shfl_xor(ss, m, 64);
      __syncthreads();                     // prior uses of red/hs complete
      if ((t & 63) == 0) red[t >> 6] = ss;
      __syncthreads();
      const float nrm = fmaxf(sqrtf(red[0] + red[1] + red[2] + red[3]), 1e-12f);
      hs[4 * t + 0] = x0 / nrm; hs[4 * t + 1] = x1 / nrm;
      hs[4 * t + 2] = x2 / nrm; hs[4 * t + 3] = x3 / nrm;
    }
    __syncthreads();
    const float4 h0v = *(const float4*)&h0s[t << 2];   // this thread's j-chunk
    float acc = 0.f;
    const int i0 = slice << 7;
    #pragma unroll 4
    for (int i = i0; i < i0 + 128; ++i) {
      const float4 g = ((const float4*)(Gf32 + (size_t)i * D))[t];
      const float d = g.x * h0v.x + g.y * h0v.y + g.z * h0v.z + g.w * h0v.w;
      acc = fmaf(h1s[i], d, acc);
    }
    #pragma unroll
    for (int m = 1; m < 64; m <<= 1) acc += __shfl_xor(acc, m, 64);
    __syncthreads();
    if ((t & 63) == 0) red[t >> 6] = acc;
    __syncthreads();
    if (t == 0) pz[(size_t)w * 8 + slice] = red[0] + red[1] + red[2] + red[3];
    __syncthreads();
  }
}

// ---------------------------------------------------------------- fixup_final
// Sum the 8 slice partials in fixed order -> exact decision -> hard[idx].
__global__ void fixup_final(const int* __restrict__ flags, const int* __restrict__ fcnt,
    const float* __restrict__ pz,
    const float* __restrict__ sig_temp, const float* __restrict__ sig_thr,
    const float* __restrict__ noise_u, unsigned char* __restrict__ hard) {
  const int w = blockIdx.x * 256 + threadIdx.x;
  const int nf = min(*fcnt, MAXF);
  if (w >= nf) return;
  const int idx = flags[w];
  float a = 0.f;
  #pragma unroll
  for (int p = 0; p < 8; ++p) a += pz[(size_t)w * 8 + p];
  const float sc = a * SCALE;
  const float temp = sig_temp[0], thr = sig_thr[0];
  float pr = 1.f / (1.f + expf(-(sc - thr) / temp));
  pr = fminf(fmaxf(pr, 0.f), 1.f);
  const float p = fminf(fmaxf(pr, FEPS), 1.f - FEPS);
  const float lgt = logf(p) - log1pf(-p);
  const float uu = fminf(fmaxf(noise_u[idx], FEPS), 1.f - FEPS);
  const float lgs = logf(uu) - log1pf(-uu);
  hard[idx] = ((lgt + lgs) > 0.f) ? 1 : 0;
}

// ---------------------------------------------------------------- decide_scan
// hard bits -> per-batch cumsum -> segment starts (no transcendentals).
__global__ void decide_scan(const unsigned char* __restrict__ hard_,
                            int* __restrict__ seg_start, int* __restrict__ nseg_out,
                            float* __restrict__ kf_out) {
  const int b = blockIdx.x, t = threadIdx.x;
  __shared__ int ssum[256];
  const uint4 hv = ((const uint4*)(hard_ + (size_t)b * S))[t];
  const uint32_t wds[4] = {hv.x, hv.y, hv.z, hv.w};
  const uint32_t bsum = hv.x + hv.y + hv.z + hv.w;     // bytewise (each <=1)
  const int loc = (int)((bsum & 255) + ((bsum >> 8) & 255) +
                        ((bsum >> 16) & 255) + (bsum >> 24));
  ssum[t] = loc;
  __syncthreads();
  for (int off = 1; off < 256; off <<= 1) {
    int v = ssum[t];
    if (t >= off) v += ssum[t - off];
    __syncthreads();
    ssum[t] = v;
    __syncthreads();
  }
  const int ktot = ssum[255];
  int cum = ssum[t] - loc;                 // exclusive prefix
  #pragma unroll
  for (int e = 0; e < 16; ++e) {
    const int s = (t << 4) + e;
    const int bit = (int)((wds[e >> 2] >> ((e & 3) * 8)) & 1);
    const int pseg = min(max(cum - 1, 0), S - 1);
    cum += bit;
    const int seg = min(max(cum - 1, 0), S - 1);
    if (s == 0 || seg != pseg) seg_start[b * S + seg] = s;
  }
  if (t == 0) {
    nseg_out[b] = min(max(ktot, 1), S);
    kf_out[b] = (float)ktot;
  }
}

// ---------------------------------------------------------------- pool
// out[j, b, :] = mean over segment j of h rows (f16->f32), zeros for j >= nseg.
__global__ void pool(const u16* __restrict__ Hf,
                     const int* __restrict__ seg_start, const int* __restrict__ nseg_arr,
                     float* __restrict__ out) {
  const int j = blockIdx.x, b = blockIdx.y, t = threadIdx.x;
  const int ns = nseg_arr[b];
  float4* o = (float4*)(out + (((size_t)j * Bb + b) << 10));
  if (j >= ns) {
    o[t] = (float4){0.f, 0.f, 0.f, 0.f};
    return;
  }
  const int s0 = seg_start[b * S + j];
  const int s1 = (j + 1 < ns) ? seg_start[b * S + j + 1] : S;
  float a0 = 0.f, a1 = 0.f, a2 = 0.f, a3 = 0.f;
  for (int s = s0; s < s1; ++s) {
    const ushort4 hv = *(const ushort4*)(Hf + (((size_t)b * S + s) << 10) + (t << 2));
    a0 += h2f(hv.x); a1 += h2f(hv.y); a2 += h2f(hv.z); a3 += h2f(hv.w);
  }
  const float c = (float)(s1 - s0);
  o[t] = (float4){a0 / c, a1 / c, a2 / c, a3 / c};
}

// ---------------------------------------------------------------- loss
__global__ void loss_k(const float* __restrict__ kf, float* __restrict__ out) {
  const int t = threadIdx.x;
  float lp = 0.f;
  if (t < 8) {
    const float n = 4096.f;
    const float k = kf[t];
    lp = lgammaf(n + 1.f) - lgammaf(k + 1.f) - lgammaf(n - k + 1.f)
       + k * logf(0.2f) + (n - k) * log1pf(-0.2f);
  }
  #pragma unroll
  for (int off = 1; off < 8; off <<= 1) lp += __shfl_xor(lp, off, 64);
  if (t == 0) out[(size_t)BS * 1024] = -(lp / 8.f) / 4096.f;
}

}  // namespace

extern "C" void kernel_launch(void* const* d_in, const int* in_sizes, int n_in,
                              void* d_out, int out_size, void* d_ws, size_t ws_size,
                              hipStream_t stream) {
  (void)in_sizes; (void)n_in; (void)out_size; (void)ws_size;
  const float* hidden = (const float*)d_in[0];
  const float* pos    = (const float*)d_in[1];
  const float* Wq     = (const float*)d_in[2];
  const float* Wk     = (const float*)d_in[3];
  const float* stemp  = (const float*)d_in[4];
  const float* sthr   = (const float*)d_in[5];
  const float* nois   = (const float*)d_in[6];
  float* out = (float*)d_out;
  char* ws = (char*)d_ws;

  // workspace layout (bytes)
  u16*   Hf        = (u16*)(ws);                       // 67,108,864 (f16 bits)
  u16*   Gf16      = (u16*)(ws + 67108864);            //  2,097,152
  float* Gf32      = (float*)(ws + 69206016);          //  4,194,304
  float* adj_part  = (float*)(ws + 73400320);          //  1,048,576 (8 x BS f32)
  unsigned char* hard = (unsigned char*)(ws + 74448896); //   32,768
  int*   flags     = (int*)(ws + 74481664);            //     16,384 (MAXF ints)
  float* pz        = (float*)(ws + 74498048);          //    131,072 (MAXF x 8 f32)
  int*   fcnt      = (int*)(ws + 74629120);            //         64
  int*   seg_start = (int*)(ws + 74629184);            //    131,072
  int*   nseg      = (int*)(ws + 74760256);            //         64
  float* kf        = (float*)(ws + 74760320);          //         32

  hipLaunchKernelGGL(prep_h,      dim3(BS),       dim3(256), 0, stream, hidden, pos, Hf, fcnt);
  hipLaunchKernelGGL(gemm_G,      dim3(16, 16),   dim3(256), 0, stream, Wq, Wk, Gf32, Gf16);
  hipLaunchKernelGGL(gemm_main,   dim3(1024),     dim3(512), 0, stream, Hf, Gf16, adj_part);
  hipLaunchKernelGGL(score_flag,  dim3(BS/256),   dim3(256), 0, stream, adj_part, stemp, sthr, nois, hard, flags, fcnt);
  hipLaunchKernelGGL(fixup_part,  dim3(256),      dim3(256), 0, stream, flags, fcnt, hidden, pos, Gf32, pz);
  hipLaunchKernelGGL(fixup_final, dim3(MAXF/256), dim3(256), 0, stream, flags, fcnt, pz, stemp, sthr, nois, hard);
  hipLaunchKernelGGL(decide_scan, dim3(Bb),       dim3(256), 0, stream, hard, seg_start, nseg, kf);
  hipLaunchKernelGGL(pool,        dim3(S, Bb),    dim3(256), 0, stream, Hf, seg_start, nseg, out);
  hipLaunchKernelGGL(loss_k,      dim3(1),        dim3(64),  0, stream, kf, out);
}

// Round 5
// 236.381 us; speedup vs baseline: 2.0813x; 1.1794x over previous
//
#include <hip/hip_runtime.h>
#include <stdint.h>

namespace {

constexpr int Bb = 8, S = 4096, D = 1024, BS = 32768;
constexpr float SCALE = 0.08838834764831845f;           // (D/NUM_HEADS)^-0.5
constexpr float FEPS  = 1.1920928955078125e-07f;        // float32 eps (2^-23)
constexpr int MAXF = 4096;                              // max rescued items

typedef unsigned short u16;
typedef __attribute__((ext_vector_type(8))) _Float16 f16x8;
typedef __attribute__((ext_vector_type(4))) float    f32x4;

__device__ __forceinline__ u16 f2h(float f) {
  _Float16 h = (_Float16)f;
  return __builtin_bit_cast(u16, h);
}
__device__ __forceinline__ float h2f(u16 u) {
  return (float)__builtin_bit_cast(_Float16, u);
}
__device__ __forceinline__ void gload_lds16(const void* g, void* l) {
  __builtin_amdgcn_global_load_lds((const __attribute__((address_space(1))) void*)g,
                                   (__attribute__((address_space(3))) void*)l, 16, 0, 0);
}
#define VMCNT(n) asm volatile("s_waitcnt vmcnt(" #n ")" ::: "memory")

// ---------------------------------------------------------------- prep_h
// h = (hidden + pos) / max(||.||2, 1e-12), stored f16. Also zeroes fcnt.
__global__ void prep_h(const float* __restrict__ hidden, const float* __restrict__ pos,
                       u16* __restrict__ Hf, int* __restrict__ fcnt) {
  if (blockIdx.x == 0 && threadIdx.x == 0) *fcnt = 0;
  const int r = blockIdx.x;          // row in [0, BS)
  const int t = threadIdx.x;         // 256 threads, 4 elems each
  const float4 hv = ((const float4*)(hidden + (size_t)r * D))[t];
  const float4 pv = ((const float4*)(pos + (size_t)(r & (S - 1)) * D))[t];
  float x0 = hv.x + pv.x, x1 = hv.y + pv.y, x2 = hv.z + pv.z, x3 = hv.w + pv.w;
  float ss = x0 * x0 + x1 * x1 + x2 * x2 + x3 * x3;
  #pragma unroll
  for (int m = 1; m < 64; m <<= 1) ss += __shfl_xor(ss, m, 64);
  __shared__ float red[4];
  if ((t & 63) == 0) red[t >> 6] = ss;
  __syncthreads();
  const float nrm = fmaxf(sqrtf(red[0] + red[1] + red[2] + red[3]), 1e-12f);
  ((ushort4*)(Hf + (size_t)r * D))[t] = make_ushort4(
      f2h(x0 / nrm), f2h(x1 / nrm), f2h(x2 / nrm), f2h(x3 / nrm));
}

// ---------------------------------------------------------------- gemm_G_part
// Partial G over K-slice z: Gpart[z][i][j] = sum_{k in slice} Wq[k][i]*Wk[k][j].
__global__ void gemm_G_part(const float* __restrict__ Wq, const float* __restrict__ Wk,
                            float* __restrict__ Gpart) {
  __shared__ float Qs[32][64];
  __shared__ float Ks[32][64];
  const int t = threadIdx.x;
  const int i0 = blockIdx.x * 64, j0 = blockIdx.y * 64;
  const int kz = blockIdx.z * 256;
  const int tx = t & 15, ty = t >> 4;
  float acc[4][4] = {};
  for (int k0 = kz; k0 < kz + 256; k0 += 32) {
    #pragma unroll
    for (int q = 0; q < 2; ++q) {
      const int c = t + q * 256;
      const int row = c >> 4, c4 = (c & 15) << 2;
      *(float4*)&Qs[row][c4] = *(const float4*)&Wq[(size_t)(k0 + row) * D + i0 + c4];
      *(float4*)&Ks[row][c4] = *(const float4*)&Wk[(size_t)(k0 + row) * D + j0 + c4];
    }
    __syncthreads();
    #pragma unroll 8
    for (int kk = 0; kk < 32; ++kk) {
      const float4 qa = *(const float4*)&Qs[kk][tx << 2];
      const float4 kb = *(const float4*)&Ks[kk][ty << 2];
      const float qq[4] = {qa.x, qa.y, qa.z, qa.w};
      const float kv[4] = {kb.x, kb.y, kb.z, kb.w};
      #pragma unroll
      for (int a = 0; a < 4; ++a)
        #pragma unroll
        for (int bj = 0; bj < 4; ++bj) acc[a][bj] = fmaf(qq[a], kv[bj], acc[a][bj]);
    }
    __syncthreads();
  }
  float* gp = Gpart + (size_t)blockIdx.z * 1048576;
  #pragma unroll
  for (int a = 0; a < 4; ++a) {
    const int i = i0 + (tx << 2) + a;
    *(float4*)&gp[(size_t)i * D + j0 + (ty << 2)] =
        make_float4(acc[a][0], acc[a][1], acc[a][2], acc[a][3]);
  }
}

// ---------------------------------------------------------------- gemm_G_comb
// Fixed-order sum of 4 K-slice partials -> Gf32 + Gf16.
__global__ void gemm_G_comb(const float* __restrict__ Gpart,
                            float* __restrict__ Gf32, u16* __restrict__ Gf16) {
  const size_t e = ((size_t)blockIdx.x * 256 + threadIdx.x) * 4;   // float4 index
  float4 a = *(const float4*)&Gpart[e];
  #pragma unroll
  for (int z = 1; z < 4; ++z) {
    const float4 p = *(const float4*)&Gpart[(size_t)z * 1048576 + e];
    a.x += p.x; a.y += p.y; a.z += p.z; a.w += p.w;
  }
  *(float4*)&Gf32[e] = a;
  *(ushort4*)&Gf16[e] = make_ushort4(f2h(a.x), f2h(a.y), f2h(a.z), f2h(a.w));
}

// ---------------------------------------------------------------- gemm_main
// fp16 MFMA GEMM, single-barrier double-buffer pipeline.
// BM=256 BN=256 BK=64, 512 thr (8 waves, 2 wr x 4 wc), per-wave 128x64 out
// (24 ds_read_b128 per 64 MFMA -> half the LDS-read pressure of 128x32).
// Schedule per tile: vmcnt(0); barrier; stage(t+1, other buf); compute(t).
// Stage-after-barrier is race-free: the barrier proves every wave finished
// its t-1 reads of the buffer being overwritten. Loads for t+1 land during
// compute(t) (~600+ cyc cover).
// Fused epilogue: adj_part[nt][r] = sum_{i in tile} U[r,i]*Hf[r+1,i].
__global__ __launch_bounds__(512, 2) void gemm_main(
    const u16* __restrict__ Hf, const u16* __restrict__ Gf,
    float* __restrict__ adj_part) {
  __shared__ u16 Abuf[2][16384];      // 2 x 32KB (256 rows x 64 k)
  __shared__ u16 Bbuf[2][16384];      // 2 x 32KB (256 rows x 64 k)
  __shared__ float adjp[4][256];

  const int tid = threadIdx.x;
  const int bid = blockIdx.x;
  const int swz = (bid & 7) * 64 + (bid >> 3);   // XCD swizzle (512 % 8 == 0)
  const int mt = swz >> 2, nt = swz & 3;
  const int r0 = mt << 8;             // 256-row block
  const int n0g = nt << 8;            // 256-col block

  const int wave = tid >> 6, lane = tid & 63;
  const int wr = wave >> 2;           // 0..1 -> rows wr*128
  const int wc = wave & 3;            // 0..3 -> cols wc*64
  const int frow = lane & 15;
  const int fgrp = lane >> 4;         // 0..3
  const int sw = (lane & 7) << 4;     // read-side swizzle (row&7 == lane&7)
  const int cb0 = (fgrp * 16) ^ sw;          // ks=0 frag byte col
  const int cb1 = (64 + fgrp * 16) ^ sw;     // ks=1 frag byte col
  const int Abase = (wr * 128 + frow) * 128; // bytes
  const int Bbase = (wc * 64 + frow) * 128;  // bytes

  const int trow = tid >> 3;                 // 0..63
  const int scb = ((tid & 7) << 4) ^ ((trow & 7) << 4);  // pre-swizzled src col
  const char* Asrc = (const char*)Hf + (size_t)(r0 + trow) * 2048 + scb;
  const char* Bsrc = (const char*)Gf + (size_t)(n0g + trow) * 2048 + scb;
  const int dst16 = tid * 16;

  f32x4 acc[8][4];
  #pragma unroll
  for (int m = 0; m < 8; ++m)
    #pragma unroll
    for (int n = 0; n < 4; ++n) acc[m][n] = (f32x4){0.f, 0.f, 0.f, 0.f};

  auto stage = [&](int b, int kt) {
    #pragma unroll
    for (int q = 0; q < 4; ++q) {
      gload_lds16(Asrc + (size_t)q * 131072 + (size_t)kt * 128,
                  (char*)&Abuf[b][0] + q * 8192 + dst16);
      gload_lds16(Bsrc + (size_t)q * 131072 + (size_t)kt * 128,
                  (char*)&Bbuf[b][0] + q * 8192 + dst16);
    }
  };

  auto compute = [&](int b) {
    const char* Ab = (const char*)&Abuf[b][0];
    const char* Bp = (const char*)&Bbuf[b][0];
    #pragma unroll
    for (int ks = 0; ks < 2; ++ks) {
      const int cb = ks ? cb1 : cb0;
      f16x8 bf[4], af[8];
      #pragma unroll
      for (int n = 0; n < 4; ++n) bf[n] = *(const f16x8*)(Bp + Bbase + n * 2048 + cb);
      #pragma unroll
      for (int m = 0; m < 8; ++m) af[m] = *(const f16x8*)(Ab + Abase + m * 2048 + cb);
      __builtin_amdgcn_s_setprio(1);
      #pragma unroll
      for (int m = 0; m < 8; ++m)
        #pragma unroll
        for (int n = 0; n < 4; ++n)
          acc[m][n] = __builtin_amdgcn_mfma_f32_16x16x32_f16(af[m], bf[n], acc[m][n], 0, 0, 0);
      __builtin_amdgcn_s_setprio(0);
    }
  };

  stage(0, 0);
  #pragma unroll 1
  for (int t = 0; t < 16; ++t) {
    VMCNT(0);                              // own loads for tile t retired to LDS
    __builtin_amdgcn_s_barrier();          // all waves: tile t visible; t-1 reads done
    __builtin_amdgcn_sched_barrier(0);
    if (t < 15) stage((t + 1) & 1, t + 1); // 8 loads fly under compute(t)
    __builtin_amdgcn_sched_barrier(0);
    compute(t & 1);
  }

  // epilogue: rowwise dot with shifted h (f16->f32), reduce over 16 lanes
  #pragma unroll
  for (int m = 0; m < 8; ++m) {
    #pragma unroll
    for (int reg = 0; reg < 4; ++reg) {
      const int rl = wr * 128 + m * 16 + fgrp * 4 + reg;
      const int gr = r0 + rl;
      float sum = 0.f;
      if (((gr + 1) & (S - 1)) != 0) {
        const u16* hrow = Hf + (size_t)(gr + 1) * D + n0g + wc * 64 + frow;
        #pragma unroll
        for (int n = 0; n < 4; ++n)
          sum = fmaf(acc[m][n][reg], h2f(hrow[n * 16]), sum);
      }
      #pragma unroll
      for (int off = 1; off < 16; off <<= 1) sum += __shfl_xor(sum, off, 64);
      if (frow == 0) adjp[wc][rl] = sum;
    }
  }
  __syncthreads();
  if (tid < 256) {
    adj_part[(size_t)nt * BS + r0 + tid] =
        adjp[0][tid] + adjp[1][tid] + adjp[2][tid] + adjp[3][tid];
  }
}

// ---------------------------------------------------------------- score_flag
// score -> decision logit z -> hard bit; flag near-threshold positions.
__global__ void score_flag(const float* __restrict__ adj_part,
                           const float* __restrict__ sig_temp, const float* __restrict__ sig_thr,
                           const float* __restrict__ noise_u,
                           unsigned char* __restrict__ hard, int* __restrict__ flags,
                           int* __restrict__ fcnt) {
  const int idx = blockIdx.x * 256 + threadIdx.x;   // position b*S + s
  const int s = idx & (S - 1);
  float sc = 0.f;
  if (s > 0) {
    float a = 0.f;
    #pragma unroll
    for (int p = 0; p < 4; ++p) a += adj_part[(size_t)p * BS + idx - 1];
    sc = a * SCALE;
  }
  const float temp = sig_temp[0], thr = sig_thr[0];
  float pr = 1.f / (1.f + expf(-(sc - thr) / temp));
  pr = fminf(fmaxf(pr, 0.f), 1.f);
  if (s == 0) pr = 1.f;
  const float p = fminf(fmaxf(pr, FEPS), 1.f - FEPS);
  const float lgt = logf(p) - log1pf(-p);
  const float uu = fminf(fmaxf(noise_u[idx], FEPS), 1.f - FEPS);
  const float lgs = logf(uu) - log1pf(-uu);
  const float z = lgt + lgs;                        // soft > 0.5 <=> z > 0
  hard[idx] = (z > 0.f) ? 1 : 0;
  if (s > 0 && fabsf(z) < 1e-3f) {                  // margin >> fp16 score error
    const int k = atomicAdd(fcnt, 1);
    if (k < MAXF) flags[k] = idx;
  }
}

// ---------------------------------------------------------------- fixup_part
// Exact f32 partial scores for flagged items. Block = (item-slot, slice);
// slice covers 128 rows of G. Coalesced float4 loads; deterministic block
// reduce -> pz[item][slice]. 256 blocks = 32 item-slots x 8 slices.
__global__ __launch_bounds__(256) void fixup_part(const int* __restrict__ flags,
    const int* __restrict__ fcnt, const float* __restrict__ hidden,
    const float* __restrict__ pos, const float* __restrict__ Gf32,
    float* __restrict__ pz) {
  __shared__ float h0s[1024];
  __shared__ float h1s[1024];
  __shared__ float red[4];
  const int t = threadIdx.x;
  const int slice = blockIdx.x & 7;
  const int nf = min(*fcnt, MAXF);
  for (int w = blockIdx.x >> 3; w < nf; w += 32) {
    const int idx = flags[w];
    #pragma unroll
    for (int rr = 0; rr < 2; ++rr) {
      const int r = idx - 1 + rr;
      float* hs = rr ? h1s : h0s;
      const float4 hv = ((const float4*)(hidden + (size_t)r * D))[t];
      const float4 pv = ((const float4*)(pos + (size_t)(r & (S - 1)) * D))[t];
      const float x0 = hv.x + pv.x, x1 = hv.y + pv.y, x2 = hv.z + pv.z, x3 = hv.w + pv.w;
      float ss = x0 * x0 + x1 * x1 + x2 * x2 + x3 * x3;
      #pragma unroll
      for (int m = 1; m < 64; m <<= 1) ss += __shfl_xor(ss, m, 64);
      __syncthreads();                     // prior uses of red/hs complete
      if ((t & 63) == 0) red[t >> 6] = ss;
      __syncthreads();
      const float nrm = fmaxf(sqrtf(red[0] + red[1] + red[2] + red[3]), 1e-12f);
      hs[4 * t + 0] = x0 / nrm; hs[4 * t + 1] = x1 / nrm;
      hs[4 * t + 2] = x2 / nrm; hs[4 * t + 3] = x3 / nrm;
    }
    __syncthreads();
    const float4 h0v = *(const float4*)&h0s[t << 2];   // this thread's j-chunk
    float acc = 0.f;
    const int i0 = slice << 7;
    #pragma unroll 4
    for (int i = i0; i < i0 + 128; ++i) {
      const float4 g = ((const float4*)(Gf32 + (size_t)i * D))[t];
      const float d = g.x * h0v.x + g.y * h0v.y + g.z * h0v.z + g.w * h0v.w;
      acc = fmaf(h1s[i], d, acc);
    }
    #pragma unroll
    for (int m = 1; m < 64; m <<= 1) acc += __shfl_xor(acc, m, 64);
    __syncthreads();
    if ((t & 63) == 0) red[t >> 6] = acc;
    __syncthreads();
    if (t == 0) pz[(size_t)w * 8 + slice] = red[0] + red[1] + red[2] + red[3];
    __syncthreads();
  }
}

// ---------------------------------------------------------------- fixup_final
// Sum the 8 slice partials in fixed order -> exact decision -> hard[idx].
__global__ void fixup_final(const int* __restrict__ flags, const int* __restrict__ fcnt,
    const float* __restrict__ pz,
    const float* __restrict__ sig_temp, const float* __restrict__ sig_thr,
    const float* __restrict__ noise_u, unsigned char* __restrict__ hard) {
  const int w = blockIdx.x * 256 + threadIdx.x;
  const int nf = min(*fcnt, MAXF);
  if (w >= nf) return;
  const int idx = flags[w];
  float a = 0.f;
  #pragma unroll
  for (int p = 0; p < 8; ++p) a += pz[(size_t)w * 8 + p];
  const float sc = a * SCALE;
  const float temp = sig_temp[0], thr = sig_thr[0];
  float pr = 1.f / (1.f + expf(-(sc - thr) / temp));
  pr = fminf(fmaxf(pr, 0.f), 1.f);
  const float p = fminf(fmaxf(pr, FEPS), 1.f - FEPS);
  const float lgt = logf(p) - log1pf(-p);
  const float uu = fminf(fmaxf(noise_u[idx], FEPS), 1.f - FEPS);
  const float lgs = logf(uu) - log1pf(-uu);
  hard[idx] = ((lgt + lgs) > 0.f) ? 1 : 0;
}

// ---------------------------------------------------------------- decide_scan
// hard bits -> per-batch cumsum -> segment starts (no transcendentals).
__global__ void decide_scan(const unsigned char* __restrict__ hard_,
                            int* __restrict__ seg_start, int* __restrict__ nseg_out,
                            float* __restrict__ kf_out) {
  const int b = blockIdx.x, t = threadIdx.x;
  __shared__ int ssum[256];
  const uint4 hv = ((const uint4*)(hard_ + (size_t)b * S))[t];
  const uint32_t wds[4] = {hv.x, hv.y, hv.z, hv.w};
  const uint32_t bsum = hv.x + hv.y + hv.z + hv.w;     // bytewise (each <=1)
  const int loc = (int)((bsum & 255) + ((bsum >> 8) & 255) +
                        ((bsum >> 16) & 255) + (bsum >> 24));
  ssum[t] = loc;
  __syncthreads();
  for (int off = 1; off < 256; off <<= 1) {
    int v = ssum[t];
    if (t >= off) v += ssum[t - off];
    __syncthreads();
    ssum[t] = v;
    __syncthreads();
  }
  const int ktot = ssum[255];
  int cum = ssum[t] - loc;                 // exclusive prefix
  #pragma unroll
  for (int e = 0; e < 16; ++e) {
    const int s = (t << 4) + e;
    const int bit = (int)((wds[e >> 2] >> ((e & 3) * 8)) & 1);
    const int pseg = min(max(cum - 1, 0), S - 1);
    cum += bit;
    const int seg = min(max(cum - 1, 0), S - 1);
    if (s == 0 || seg != pseg) seg_start[b * S + seg] = s;
  }
  if (t == 0) {
    nseg_out[b] = min(max(ktot, 1), S);
    kf_out[b] = (float)ktot;
  }
}

// ---------------------------------------------------------------- pool
// out[j, b, :] = mean over segment j of h rows (f16->f32), zeros for j >= nseg.
__global__ void pool(const u16* __restrict__ Hf,
                     const int* __restrict__ seg_start, const int* __restrict__ nseg_arr,
                     float* __restrict__ out) {
  const int j = blockIdx.x, b = blockIdx.y, t = threadIdx.x;
  const int ns = nseg_arr[b];
  float4* o = (float4*)(out + (((size_t)j * Bb + b) << 10));
  if (j >= ns) {
    o[t] = (float4){0.f, 0.f, 0.f, 0.f};
    return;
  }
  const int s0 = seg_start[b * S + j];
  const int s1 = (j + 1 < ns) ? seg_start[b * S + j + 1] : S;
  float a0 = 0.f, a1 = 0.f, a2 = 0.f, a3 = 0.f;
  for (int s = s0; s < s1; ++s) {
    const ushort4 hv = *(const ushort4*)(Hf + (((size_t)b * S + s) << 10) + (t << 2));
    a0 += h2f(hv.x); a1 += h2f(hv.y); a2 += h2f(hv.z); a3 += h2f(hv.w);
  }
  const float c = (float)(s1 - s0);
  o[t] = (float4){a0 / c, a1 / c, a2 / c, a3 / c};
}

// ---------------------------------------------------------------- loss
__global__ void loss_k(const float* __restrict__ kf, float* __restrict__ out) {
  const int t = threadIdx.x;
  float lp = 0.f;
  if (t < 8) {
    const float n = 4096.f;
    const float k = kf[t];
    lp = lgammaf(n + 1.f) - lgammaf(k + 1.f) - lgammaf(n - k + 1.f)
       + k * logf(0.2f) + (n - k) * log1pf(-0.2f);
  }
  #pragma unroll
  for (int off = 1; off < 8; off <<= 1) lp += __shfl_xor(lp, off, 64);
  if (t == 0) out[(size_t)BS * 1024] = -(lp / 8.f) / 4096.f;
}

}  // namespace

extern "C" void kernel_launch(void* const* d_in, const int* in_sizes, int n_in,
                              void* d_out, int out_size, void* d_ws, size_t ws_size,
                              hipStream_t stream) {
  (void)in_sizes; (void)n_in; (void)out_size; (void)ws_size;
  const float* hidden = (const float*)d_in[0];
  const float* pos    = (const float*)d_in[1];
  const float* Wq     = (const float*)d_in[2];
  const float* Wk     = (const float*)d_in[3];
  const float* stemp  = (const float*)d_in[4];
  const float* sthr   = (const float*)d_in[5];
  const float* nois   = (const float*)d_in[6];
  float* out = (float*)d_out;
  char* ws = (char*)d_ws;

  // workspace layout (bytes)
  u16*   Hf        = (u16*)(ws);                       // 67,108,864 (f16 bits)
  u16*   Gf16      = (u16*)(ws + 67108864);            //  2,097,152
  float* Gf32      = (float*)(ws + 69206016);          //  4,194,304
  float* adj_part  = (float*)(ws + 73400320);          //  1,048,576 (4 x BS f32 used)
  unsigned char* hard = (unsigned char*)(ws + 74448896); //   32,768
  int*   flags     = (int*)(ws + 74481664);            //     16,384 (MAXF ints)
  float* pz        = (float*)(ws + 74498048);          //    131,072 (MAXF x 8 f32)
  int*   fcnt      = (int*)(ws + 74629120);            //         64
  int*   seg_start = (int*)(ws + 74629184);            //    131,072
  int*   nseg      = (int*)(ws + 74760256);            //         64
  float* kf        = (float*)(ws + 74760320);          //         64
  float* Gpart     = (float*)(ws + 74760384);          // 16,777,216 (4 x 1024^2 f32)

  hipLaunchKernelGGL(prep_h,      dim3(BS),         dim3(256), 0, stream, hidden, pos, Hf, fcnt);
  hipLaunchKernelGGL(gemm_G_part, dim3(16, 16, 4),  dim3(256), 0, stream, Wq, Wk, Gpart);
  hipLaunchKernelGGL(gemm_G_comb, dim3(1024),       dim3(256), 0, stream, Gpart, Gf32, Gf16);
  hipLaunchKernelGGL(gemm_main,   dim3(512),        dim3(512), 0, stream, Hf, Gf16, adj_part);
  hipLaunchKernelGGL(score_flag,  dim3(BS/256),     dim3(256), 0, stream, adj_part, stemp, sthr, nois, hard, flags, fcnt);
  hipLaunchKernelGGL(fixup_part,  dim3(256),        dim3(256), 0, stream, flags, fcnt, hidden, pos, Gf32, pz);
  hipLaunchKernelGGL(fixup_final, dim3(MAXF/256),   dim3(256), 0, stream, flags, fcnt, pz, stemp, sthr, nois, hard);
  hipLaunchKernelGGL(decide_scan, dim3(Bb),         dim3(256), 0, stream, hard, seg_start, nseg, kf);
  hipLaunchKernelGGL(pool,        dim3(S, Bb),      dim3(256), 0, stream, Hf, seg_start, nseg, out);
  hipLaunchKernelGGL(loss_k,      dim3(1),          dim3(64),  0, stream, kf, out);
}

// Round 6
// 232.842 us; speedup vs baseline: 2.1129x; 1.0152x over previous
//
#include <hip/hip_runtime.h>
#include <stdint.h>

namespace {

constexpr int Bb = 8, S = 4096, D = 1024, BS = 32768;
constexpr float SCALE = 0.08838834764831845f;           // (D/NUM_HEADS)^-0.5
constexpr float FEPS  = 1.1920928955078125e-07f;        // float32 eps (2^-23)
constexpr int MAXF = 4096;                              // max rescued items

typedef unsigned short u16;
typedef __attribute__((ext_vector_type(8))) _Float16 f16x8;
typedef __attribute__((ext_vector_type(4))) float    f32x4;

__device__ __forceinline__ u16 f2h(float f) {
  _Float16 h = (_Float16)f;
  return __builtin_bit_cast(u16, h);
}
__device__ __forceinline__ float h2f(u16 u) {
  return (float)__builtin_bit_cast(_Float16, u);
}
__device__ __forceinline__ void gload_lds16(const void* g, void* l) {
  __builtin_amdgcn_global_load_lds((const __attribute__((address_space(1))) void*)g,
                                   (__attribute__((address_space(3))) void*)l, 16, 0, 0);
}
#define VMCNT(n) asm volatile("s_waitcnt vmcnt(" #n ")" ::: "memory")
#define LGKM0 asm volatile("s_waitcnt lgkmcnt(0)" ::: "memory")

// ---------------------------------------------------------------- prep_h
__global__ void prep_h(const float* __restrict__ hidden, const float* __restrict__ pos,
                       u16* __restrict__ Hf, int* __restrict__ fcnt) {
  if (blockIdx.x == 0 && threadIdx.x == 0) *fcnt = 0;
  const int r = blockIdx.x;
  const int t = threadIdx.x;
  const float4 hv = ((const float4*)(hidden + (size_t)r * D))[t];
  const float4 pv = ((const float4*)(pos + (size_t)(r & (S - 1)) * D))[t];
  float x0 = hv.x + pv.x, x1 = hv.y + pv.y, x2 = hv.z + pv.z, x3 = hv.w + pv.w;
  float ss = x0 * x0 + x1 * x1 + x2 * x2 + x3 * x3;
  #pragma unroll
  for (int m = 1; m < 64; m <<= 1) ss += __shfl_xor(ss, m, 64);
  __shared__ float red[4];
  if ((t & 63) == 0) red[t >> 6] = ss;
  __syncthreads();
  const float nrm = fmaxf(sqrtf(red[0] + red[1] + red[2] + red[3]), 1e-12f);
  ((ushort4*)(Hf + (size_t)r * D))[t] = make_ushort4(
      f2h(x0 / nrm), f2h(x1 / nrm), f2h(x2 / nrm), f2h(x3 / nrm));
}

// ---------------------------------------------------------------- gemm_G_part
__global__ void gemm_G_part(const float* __restrict__ Wq, const float* __restrict__ Wk,
                            float* __restrict__ Gpart) {
  __shared__ float Qs[32][64];
  __shared__ float Ks[32][64];
  const int t = threadIdx.x;
  const int i0 = blockIdx.x * 64, j0 = blockIdx.y * 64;
  const int kz = blockIdx.z * 256;
  const int tx = t & 15, ty = t >> 4;
  float acc[4][4] = {};
  for (int k0 = kz; k0 < kz + 256; k0 += 32) {
    #pragma unroll
    for (int q = 0; q < 2; ++q) {
      const int c = t + q * 256;
      const int row = c >> 4, c4 = (c & 15) << 2;
      *(float4*)&Qs[row][c4] = *(const float4*)&Wq[(size_t)(k0 + row) * D + i0 + c4];
      *(float4*)&Ks[row][c4] = *(const float4*)&Wk[(size_t)(k0 + row) * D + j0 + c4];
    }
    __syncthreads();
    #pragma unroll 8
    for (int kk = 0; kk < 32; ++kk) {
      const float4 qa = *(const float4*)&Qs[kk][tx << 2];
      const float4 kb = *(const float4*)&Ks[kk][ty << 2];
      const float qq[4] = {qa.x, qa.y, qa.z, qa.w};
      const float kv[4] = {kb.x, kb.y, kb.z, kb.w};
      #pragma unroll
      for (int a = 0; a < 4; ++a)
        #pragma unroll
        for (int bj = 0; bj < 4; ++bj) acc[a][bj] = fmaf(qq[a], kv[bj], acc[a][bj]);
    }
    __syncthreads();
  }
  float* gp = Gpart + (size_t)blockIdx.z * 1048576;
  #pragma unroll
  for (int a = 0; a < 4; ++a) {
    const int i = i0 + (tx << 2) + a;
    *(float4*)&gp[(size_t)i * D + j0 + (ty << 2)] =
        make_float4(acc[a][0], acc[a][1], acc[a][2], acc[a][3]);
  }
}

// ---------------------------------------------------------------- gemm_G_comb
__global__ void gemm_G_comb(const float* __restrict__ Gpart,
                            float* __restrict__ Gf32, u16* __restrict__ Gf16) {
  const size_t e = ((size_t)blockIdx.x * 256 + threadIdx.x) * 4;
  float4 a = *(const float4*)&Gpart[e];
  #pragma unroll
  for (int z = 1; z < 4; ++z) {
    const float4 p = *(const float4*)&Gpart[(size_t)z * 1048576 + e];
    a.x += p.x; a.y += p.y; a.z += p.z; a.w += p.w;
  }
  *(float4*)&Gf32[e] = a;
  *(ushort4*)&Gf16[e] = make_ushort4(f2h(a.x), f2h(a.y), f2h(a.z), f2h(a.w));
}

// ---------------------------------------------------------------- gemm_main
// fp16 MFMA GEMM, fine-phase pipeline (T2+T3+T4+T5).
// BM=BN=256 BK=64, 8 waves (2 wr x 4 wc), per-wave 128x64.
// 2 LDS slots; tile t+1 staged DURING tile t in 6 quarter-units ordered by
// next-tile first use: {B-n01, B-n23, A-q0, A-q1, A-q2, A-q3}. Per tile, 4
// phases; each phase: {vmcnt(N); bar; ds_reads; stage; bar; lgkm0; SB;
// setprio1; 16 MFMA; setprio0}. Counted waits N={3,4,5,6} (never 0 until
// tile 15). WAR-safe: stages target the other slot whose reads finished >=3
// barriers earlier. Fused epilogue: adj_part[nt][r] = sum_i U[r,i]*Hf[r+1,i].
__global__ __launch_bounds__(512, 2) void gemm_main(
    const u16* __restrict__ Hf, const u16* __restrict__ Gf,
    float* __restrict__ adj_part) {
  __shared__ u16 Abuf[2][16384];      // 2 x 32KB (256 rows x 64 k)
  __shared__ u16 Bbuf[2][16384];
  __shared__ float adjp[4][256];

  const int tid = threadIdx.x;
  const int bid = blockIdx.x;
  const int swz = (bid & 7) * 64 + (bid >> 3);   // XCD swizzle (512 % 8 == 0)
  const int mt = swz >> 2, nt = swz & 3;
  const int r0 = mt << 8;
  const int n0g = nt << 8;

  const int wave = tid >> 6, lane = tid & 63;
  const int wr = wave >> 2;           // 0..1 -> rows wr*128
  const int wc = wave & 3;            // 0..3 -> cols wc*64
  const int frow = lane & 15;
  const int fgrp = lane >> 4;
  const int sw = (lane & 7) << 4;
  const int cb0 = (fgrp * 16) ^ sw;
  const int cb1 = (64 + fgrp * 16) ^ sw;
  const int ABrow = wr * 128 + frow;
  const int Brow = wc * 64 + frow;

  const int subrow = tid >> 3;               // 0..63
  const int chunk = tid & 7;
  const int scb = (chunk << 4) ^ ((subrow & 7) << 4);  // pre-swizzled src col
  const char* HfB = (const char*)Hf;
  const char* GfB = (const char*)Gf;
  char* AbB = (char*)&Abuf[0][0];
  char* BbB = (char*)&Bbuf[0][0];

  f32x4 acc[8][4];
  #pragma unroll
  for (int m = 0; m < 8; ++m)
    #pragma unroll
    for (int n = 0; n < 4; ++n) acc[m][n] = (f32x4){0.f, 0.f, 0.f, 0.f};

  // stage one A quarter-unit q (rows [32q,32q+32) of both wr-halves), 1 load
  auto stAq = [&](char* dst, int kt, int q) {
    const int row = 32 * q + (subrow & 31) + ((subrow >> 5) << 7);
    gload_lds16(HfB + (size_t)(r0 + row) * 2048 + (size_t)kt * 128 + scb,
                dst + row * 128 + (chunk << 4));
  };
  // stage one B half-unit u (cols n01 (u=0) / n23 (u=1) of all 4 wc strips), 2 loads
  auto stBh = [&](char* dst, int kt, int u) {
    {
      const int rb = subrow;
      const int cr = ((rb >> 5) << 6) + (rb & 31) + (u << 5);
      gload_lds16(GfB + (size_t)(n0g + cr) * 2048 + (size_t)kt * 128 + scb,
                  dst + cr * 128 + (chunk << 4));
    }
    {
      const int rb = 64 + subrow;
      const int cr = ((rb >> 5) << 6) + (rb & 31) + (u << 5);
      gload_lds16(GfB + (size_t)(n0g + cr) * 2048 + (size_t)kt * 128 + scb,
                  dst + cr * 128 + (chunk << 4));
    }
  };

  f16x8 a[2][2], b[4][2];

#define READ_A(Q) \
  a[0][0] = *(const f16x8*)(Ac + (ABrow + (2*(Q)) * 16) * 128 + cb0); \
  a[0][1] = *(const f16x8*)(Ac + (ABrow + (2*(Q)) * 16) * 128 + cb1); \
  a[1][0] = *(const f16x8*)(Ac + (ABrow + (2*(Q)+1) * 16) * 128 + cb0); \
  a[1][1] = *(const f16x8*)(Ac + (ABrow + (2*(Q)+1) * 16) * 128 + cb1);

#define MFMA8(MI, Q) \
  acc[2*(Q)+(MI)][0] = __builtin_amdgcn_mfma_f32_16x16x32_f16(a[MI][0], b[0][0], acc[2*(Q)+(MI)][0], 0, 0, 0); \
  acc[2*(Q)+(MI)][0] = __builtin_amdgcn_mfma_f32_16x16x32_f16(a[MI][1], b[0][1], acc[2*(Q)+(MI)][0], 0, 0, 0); \
  acc[2*(Q)+(MI)][1] = __builtin_amdgcn_mfma_f32_16x16x32_f16(a[MI][0], b[1][0], acc[2*(Q)+(MI)][1], 0, 0, 0); \
  acc[2*(Q)+(MI)][1] = __builtin_amdgcn_mfma_f32_16x16x32_f16(a[MI][1], b[1][1], acc[2*(Q)+(MI)][1], 0, 0, 0); \
  acc[2*(Q)+(MI)][2] = __builtin_amdgcn_mfma_f32_16x16x32_f16(a[MI][0], b[2][0], acc[2*(Q)+(MI)][2], 0, 0, 0); \
  acc[2*(Q)+(MI)][2] = __builtin_amdgcn_mfma_f32_16x16x32_f16(a[MI][1], b[2][1], acc[2*(Q)+(MI)][2], 0, 0, 0); \
  acc[2*(Q)+(MI)][3] = __builtin_amdgcn_mfma_f32_16x16x32_f16(a[MI][0], b[3][0], acc[2*(Q)+(MI)][3], 0, 0, 0); \
  acc[2*(Q)+(MI)][3] = __builtin_amdgcn_mfma_f32_16x16x32_f16(a[MI][1], b[3][1], acc[2*(Q)+(MI)][3], 0, 0, 0);

#define SB __builtin_amdgcn_sched_barrier(0)
#define BAR __builtin_amdgcn_s_barrier()

  // prologue: stage tile 0 into slot 0 (issue order: Bn01, Bn23, A q0..q3)
  stBh(BbB, 0, 0);
  stBh(BbB, 0, 1);
  stAq(AbB, 0, 0); stAq(AbB, 0, 1); stAq(AbB, 0, 2); stAq(AbB, 0, 3);

  #pragma unroll 1
  for (int t = 0; t < 16; ++t) {
    const int cs = t & 1;
    char* Ac = AbB + (size_t)cs * 32768;
    char* Bc = BbB + (size_t)cs * 32768;
    char* An = AbB + (size_t)(cs ^ 1) * 32768;
    char* Bn = BbB + (size_t)(cs ^ 1) * 32768;
    const bool hn = (t < 15);

    // ---- phase 0: m0,1 x n0-3 (needs Bn01, Bn23, A-q0 of tile t)
    VMCNT(3);
    BAR;
    READ_A(0);
    #pragma unroll
    for (int n = 0; n < 4; ++n) {
      b[n][0] = *(const f16x8*)(Bc + (Brow + n * 16) * 128 + cb0);
      b[n][1] = *(const f16x8*)(Bc + (Brow + n * 16) * 128 + cb1);
    }
    if (hn) stBh(Bn, t + 1, 0);
    BAR;
    LGKM0; SB;
    __builtin_amdgcn_s_setprio(1);
    MFMA8(0, 0) MFMA8(1, 0)
    __builtin_amdgcn_s_setprio(0);

    // ---- phase 1: m2,3 (needs A-q1)
    if (hn) { VMCNT(4); } else { VMCNT(2); }
    BAR;
    READ_A(1);
    if (hn) stBh(Bn, t + 1, 1);
    BAR;
    LGKM0; SB;
    __builtin_amdgcn_s_setprio(1);
    MFMA8(0, 1) MFMA8(1, 1)
    __builtin_amdgcn_s_setprio(0);

    // ---- phase 2: m4,5 (needs A-q2)
    if (hn) { VMCNT(5); } else { VMCNT(1); }
    BAR;
    READ_A(2);
    if (hn) { stAq(An, t + 1, 0); stAq(An, t + 1, 1); }
    BAR;
    LGKM0; SB;
    __builtin_amdgcn_s_setprio(1);
    MFMA8(0, 2) MFMA8(1, 2)
    __builtin_amdgcn_s_setprio(0);

    // ---- phase 3: m6,7 (needs A-q3)
    if (hn) { VMCNT(6); } else { VMCNT(0); }
    BAR;
    READ_A(3);
    if (hn) { stAq(An, t + 1, 2); stAq(An, t + 1, 3); }
    BAR;
    LGKM0; SB;
    __builtin_amdgcn_s_setprio(1);
    MFMA8(0, 3) MFMA8(1, 3)
    __builtin_amdgcn_s_setprio(0);
  }

  // epilogue: rowwise dot with shifted h (f16->f32), reduce over 16 lanes
  #pragma unroll
  for (int m = 0; m < 8; ++m) {
    #pragma unroll
    for (int reg = 0; reg < 4; ++reg) {
      const int rl = wr * 128 + m * 16 + fgrp * 4 + reg;
      const int gr = r0 + rl;
      float sum = 0.f;
      if (((gr + 1) & (S - 1)) != 0) {
        const u16* hrow = Hf + (size_t)(gr + 1) * D + n0g + wc * 64 + frow;
        #pragma unroll
        for (int n = 0; n < 4; ++n)
          sum = fmaf(acc[m][n][reg], h2f(hrow[n * 16]), sum);
      }
      #pragma unroll
      for (int off = 1; off < 16; off <<= 1) sum += __shfl_xor(sum, off, 64);
      if (frow == 0) adjp[wc][rl] = sum;
    }
  }
  __syncthreads();
  if (tid < 256) {
    adj_part[(size_t)nt * BS + r0 + tid] =
        adjp[0][tid] + adjp[1][tid] + adjp[2][tid] + adjp[3][tid];
  }
#undef READ_A
#undef MFMA8
#undef SB
#undef BAR
}

// ---------------------------------------------------------------- score_flag
__global__ void score_flag(const float* __restrict__ adj_part,
                           const float* __restrict__ sig_temp, const float* __restrict__ sig_thr,
                           const float* __restrict__ noise_u,
                           unsigned char* __restrict__ hard, int* __restrict__ flags,
                           int* __restrict__ fcnt) {
  const int idx = blockIdx.x * 256 + threadIdx.x;
  const int s = idx & (S - 1);
  float sc = 0.f;
  if (s > 0) {
    float a = 0.f;
    #pragma unroll
    for (int p = 0; p < 4; ++p) a += adj_part[(size_t)p * BS + idx - 1];
    sc = a * SCALE;
  }
  const float temp = sig_temp[0], thr = sig_thr[0];
  float pr = 1.f / (1.f + expf(-(sc - thr) / temp));
  pr = fminf(fmaxf(pr, 0.f), 1.f);
  if (s == 0) pr = 1.f;
  const float p = fminf(fmaxf(pr, FEPS), 1.f - FEPS);
  const float lgt = logf(p) - log1pf(-p);
  const float uu = fminf(fmaxf(noise_u[idx], FEPS), 1.f - FEPS);
  const float lgs = logf(uu) - log1pf(-uu);
  const float z = lgt + lgs;
  hard[idx] = (z > 0.f) ? 1 : 0;
  if (s > 0 && fabsf(z) < 1e-3f) {
    const int k = atomicAdd(fcnt, 1);
    if (k < MAXF) flags[k] = idx;
  }
}

// ---------------------------------------------------------------- fixup_part
__global__ __launch_bounds__(256) void fixup_part(const int* __restrict__ flags,
    const int* __restrict__ fcnt, const float* __restrict__ hidden,
    const float* __restrict__ pos, const float* __restrict__ Gf32,
    float* __restrict__ pz) {
  __shared__ float h0s[1024];
  __shared__ float h1s[1024];
  __shared__ float red[4];
  const int t = threadIdx.x;
  const int slice = blockIdx.x & 7;
  const int nf = min(*fcnt, MAXF);
  for (int w = blockIdx.x >> 3; w < nf; w += 32) {
    const int idx = flags[w];
    #pragma unroll
    for (int rr = 0; rr < 2; ++rr) {
      const int r = idx - 1 + rr;
      float* hs = rr ? h1s : h0s;
      const float4 hv = ((const float4*)(hidden + (size_t)r * D))[t];
      const float4 pv = ((const float4*)(pos + (size_t)(r & (S - 1)) * D))[t];
      const float x0 = hv.x + pv.x, x1 = hv.y + pv.y, x2 = hv.z + pv.z, x3 = hv.w + pv.w;
      float ss = x0 * x0 + x1 * x1 + x2 * x2 + x3 * x3;
      #pragma unroll
      for (int m = 1; m < 64; m <<= 1) ss += __shfl_xor(ss, m, 64);
      __syncthreads();
      if ((t & 63) == 0) red[t >> 6] = ss;
      __syncthreads();
      const float nrm = fmaxf(sqrtf(red[0] + red[1] + red[2] + red[3]), 1e-12f);
      hs[4 * t + 0] = x0 / nrm; hs[4 * t + 1] = x1 / nrm;
      hs[4 * t + 2] = x2 / nrm; hs[4 * t + 3] = x3 / nrm;
    }
    __syncthreads();
    const float4 h0v = *(const float4*)&h0s[t << 2];
    float acc = 0.f;
    const int i0 = slice << 7;
    #pragma unroll 4
    for (int i = i0; i < i0 + 128; ++i) {
      const float4 g = ((const float4*)(Gf32 + (size_t)i * D))[t];
      const float d = g.x * h0v.x + g.y * h0v.y + g.z * h0v.z + g.w * h0v.w;
      acc = fmaf(h1s[i], d, acc);
    }
    #pragma unroll
    for (int m = 1; m < 64; m <<= 1) acc += __shfl_xor(acc, m, 64);
    __syncthreads();
    if ((t & 63) == 0) red[t >> 6] = acc;
    __syncthreads();
    if (t == 0) pz[(size_t)w * 8 + slice] = red[0] + red[1] + red[2] + red[3];
    __syncthreads();
  }
}

// ---------------------------------------------------------------- fixup_final
__global__ void fixup_final(const int* __restrict__ flags, const int* __restrict__ fcnt,
    const float* __restrict__ pz,
    const float* __restrict__ sig_temp, const float* __restrict__ sig_thr,
    const float* __restrict__ noise_u, unsigned char* __restrict__ hard) {
  const int w = blockIdx.x * 256 + threadIdx.x;
  const int nf = min(*fcnt, MAXF);
  if (w >= nf) return;
  const int idx = flags[w];
  float a = 0.f;
  #pragma unroll
  for (int p = 0; p < 8; ++p) a += pz[(size_t)w * 8 + p];
  const float sc = a * SCALE;
  const float temp = sig_temp[0], thr = sig_thr[0];
  float pr = 1.f / (1.f + expf(-(sc - thr) / temp));
  pr = fminf(fmaxf(pr, 0.f), 1.f);
  const float p = fminf(fmaxf(pr, FEPS), 1.f - FEPS);
  const float lgt = logf(p) - log1pf(-p);
  const float uu = fminf(fmaxf(noise_u[idx], FEPS), 1.f - FEPS);
  const float lgs = logf(uu) - log1pf(-uu);
  hard[idx] = ((lgt + lgs) > 0.f) ? 1 : 0;
}

// ---------------------------------------------------------------- decide_scan
__global__ void decide_scan(const unsigned char* __restrict__ hard_,
                            int* __restrict__ seg_start, int* __restrict__ nseg_out,
                            float* __restrict__ kf_out) {
  const int b = blockIdx.x, t = threadIdx.x;
  __shared__ int ssum[256];
  const uint4 hv = ((const uint4*)(hard_ + (size_t)b * S))[t];
  const uint32_t wds[4] = {hv.x, hv.y, hv.z, hv.w};
  const uint32_t bsum = hv.x + hv.y + hv.z + hv.w;
  const int loc = (int)((bsum & 255) + ((bsum >> 8) & 255) +
                        ((bsum >> 16) & 255) + (bsum >> 24));
  ssum[t] = loc;
  __syncthreads();
  for (int off = 1; off < 256; off <<= 1) {
    int v = ssum[t];
    if (t >= off) v += ssum[t - off];
    __syncthreads();
    ssum[t] = v;
    __syncthreads();
  }
  const int ktot = ssum[255];
  int cum = ssum[t] - loc;
  #pragma unroll
  for (int e = 0; e < 16; ++e) {
    const int s = (t << 4) + e;
    const int bit = (int)((wds[e >> 2] >> ((e & 3) * 8)) & 1);
    const int pseg = min(max(cum - 1, 0), S - 1);
    cum += bit;
    const int seg = min(max(cum - 1, 0), S - 1);
    if (s == 0 || seg != pseg) seg_start[b * S + seg] = s;
  }
  if (t == 0) {
    nseg_out[b] = min(max(ktot, 1), S);
    kf_out[b] = (float)ktot;
  }
}

// ---------------------------------------------------------------- pool
__global__ void pool(const u16* __restrict__ Hf,
                     const int* __restrict__ seg_start, const int* __restrict__ nseg_arr,
                     float* __restrict__ out) {
  const int j = blockIdx.x, b = blockIdx.y, t = threadIdx.x;
  const int ns = nseg_arr[b];
  float4* o = (float4*)(out + (((size_t)j * Bb + b) << 10));
  if (j >= ns) {
    o[t] = (float4){0.f, 0.f, 0.f, 0.f};
    return;
  }
  const int s0 = seg_start[b * S + j];
  const int s1 = (j + 1 < ns) ? seg_start[b * S + j + 1] : S;
  float a0 = 0.f, a1 = 0.f, a2 = 0.f, a3 = 0.f;
  for (int s = s0; s < s1; ++s) {
    const ushort4 hv = *(const ushort4*)(Hf + (((size_t)b * S + s) << 10) + (t << 2));
    a0 += h2f(hv.x); a1 += h2f(hv.y); a2 += h2f(hv.z); a3 += h2f(hv.w);
  }
  const float c = (float)(s1 - s0);
  o[t] = (float4){a0 / c, a1 / c, a2 / c, a3 / c};
}

// ---------------------------------------------------------------- loss
__global__ void loss_k(const float* __restrict__ kf, float* __restrict__ out) {
  const int t = threadIdx.x;
  float lp = 0.f;
  if (t < 8) {
    const float n = 4096.f;
    const float k = kf[t];
    lp = lgammaf(n + 1.f) - lgammaf(k + 1.f) - lgammaf(n - k + 1.f)
       + k * logf(0.2f) + (n - k) * log1pf(-0.2f);
  }
  #pragma unroll
  for (int off = 1; off < 8; off <<= 1) lp += __shfl_xor(lp, off, 64);
  if (t == 0) out[(size_t)BS * 1024] = -(lp / 8.f) / 4096.f;
}

}  // namespace

extern "C" void kernel_launch(void* const* d_in, const int* in_sizes, int n_in,
                              void* d_out, int out_size, void* d_ws, size_t ws_size,
                              hipStream_t stream) {
  (void)in_sizes; (void)n_in; (void)out_size; (void)ws_size;
  const float* hidden = (const float*)d_in[0];
  const float* pos    = (const float*)d_in[1];
  const float* Wq     = (const float*)d_in[2];
  const float* Wk     = (const float*)d_in[3];
  const float* stemp  = (const float*)d_in[4];
  const float* sthr   = (const float*)d_in[5];
  const float* nois   = (const float*)d_in[6];
  float* out = (float*)d_out;
  char* ws = (char*)d_ws;

  // workspace layout (bytes)
  u16*   Hf        = (u16*)(ws);                       // 67,108,864 (f16 bits)
  u16*   Gf16      = (u16*)(ws + 67108864);            //  2,097,152
  float* Gf32      = (float*)(ws + 69206016);          //  4,194,304
  float* adj_part  = (float*)(ws + 73400320);          //  1,048,576 (4 x BS f32 used)
  unsigned char* hard = (unsigned char*)(ws + 74448896); //   32,768
  int*   flags     = (int*)(ws + 74481664);            //     16,384 (MAXF ints)
  float* pz        = (float*)(ws + 74498048);          //    131,072 (MAXF x 8 f32)
  int*   fcnt      = (int*)(ws + 74629120);            //         64
  int*   seg_start = (int*)(ws + 74629184);            //    131,072
  int*   nseg      = (int*)(ws + 74760256);            //         64
  float* kf        = (float*)(ws + 74760320);          //         64
  float* Gpart     = (float*)(ws + 74760384);          // 16,777,216 (4 x 1024^2 f32)

  hipLaunchKernelGGL(prep_h,      dim3(BS),         dim3(256), 0, stream, hidden, pos, Hf, fcnt);
  hipLaunchKernelGGL(gemm_G_part, dim3(16, 16, 4),  dim3(256), 0, stream, Wq, Wk, Gpart);
  hipLaunchKernelGGL(gemm_G_comb, dim3(1024),       dim3(256), 0, stream, Gpart, Gf32, Gf16);
  hipLaunchKernelGGL(gemm_main,   dim3(512),        dim3(512), 0, stream, Hf, Gf16, adj_part);
  hipLaunchKernelGGL(score_flag,  dim3(BS/256),     dim3(256), 0, stream, adj_part, stemp, sthr, nois, hard, flags, fcnt);
  hipLaunchKernelGGL(fixup_part,  dim3(256),        dim3(256), 0, stream, flags, fcnt, hidden, pos, Gf32, pz);
  hipLaunchKernelGGL(fixup_final, dim3(MAXF/256),   dim3(256), 0, stream, flags, fcnt, pz, stemp, sthr, nois, hard);
  hipLaunchKernelGGL(decide_scan, dim3(Bb),         dim3(256), 0, stream, hard, seg_start, nseg, kf);
  hipLaunchKernelGGL(pool,        dim3(S, Bb),      dim3(256), 0, stream, Hf, seg_start, nseg, out);
  hipLaunchKernelGGL(loss_k,      dim3(1),          dim3(64),  0, stream, kf, out);
}